// Round 13
// baseline (114.674 us; speedup 1.0000x reference)
//
#include <hip/hip_runtime.h>
#include <math.h>

#define T_SEQ 2048
#define D_MODEL 1024
#define NH 16
#define HD 64
#define RMS_EPS 1.1920928955078125e-07f

typedef unsigned short ushort_t;
typedef __attribute__((ext_vector_type(8))) short short8;
typedef __attribute__((ext_vector_type(8))) unsigned short ushort8;
typedef __attribute__((ext_vector_type(4))) float f32x4;

static __device__ __forceinline__ unsigned short f2bf(float f) {
    union { float f; unsigned u; } v; v.f = f;
    unsigned r = v.u + 0x7fff + ((v.u >> 16) & 1);   // RNE
    return (unsigned short)(r >> 16);
}
static __device__ __forceinline__ float bf2f(unsigned short b) {
    union { unsigned u; float f; } v; v.u = ((unsigned)b) << 16;
    return v.f;
}
static __device__ __forceinline__ unsigned cvt_pk_bf16(float lo, float hi) {
    unsigned r;
    asm("v_cvt_pk_bf16_f32 %0, %1, %2" : "=v"(r) : "v"(lo), "v"(hi));
    return r;
}
static __device__ __forceinline__ void gl_lds16(const ushort_t* g, ushort_t* l) {
    __builtin_amdgcn_global_load_lds(
        (const __attribute__((address_space(1))) unsigned int*)g,
        (__attribute__((address_space(3))) unsigned int*)l, 16, 0, 0);
}

// ---------------------------------------------------------------------------
// Cast f32 -> bf16: x (2M elements, segs 0-1) and the 4 weights (1M each).
// ---------------------------------------------------------------------------
__global__ __launch_bounds__(256) void cast_to_bf16(
    const float* __restrict__ x, const float* __restrict__ wq,
    const float* __restrict__ wk, const float* __restrict__ wv,
    const float* __restrict__ wo,
    ushort_t* __restrict__ xb, ushort_t* __restrict__ wqb,
    ushort_t* __restrict__ wkb, ushort_t* __restrict__ wvb,
    ushort_t* __restrict__ wob) {
    const int seg = blockIdx.y;
    const float* src; ushort_t* dst; size_t base = 0;
    if (seg == 0)      { src = x;  dst = xb; }
    else if (seg == 1) { src = x;  dst = xb; base = 1u << 20; }
    else if (seg == 2) { src = wq; dst = wqb; }
    else if (seg == 3) { src = wk; dst = wkb; }
    else if (seg == 4) { src = wv; dst = wvb; }
    else               { src = wo; dst = wob; }
    const size_t i = base + ((size_t)blockIdx.x * 256 + threadIdx.x) * 8;
    float4 a = *(const float4*)&src[i];
    float4 b = *(const float4*)&src[i + 4];
    ushort8 o;
    o[0] = f2bf(a.x); o[1] = f2bf(a.y); o[2] = f2bf(a.z); o[3] = f2bf(a.w);
    o[4] = f2bf(b.x); o[5] = f2bf(b.y); o[6] = f2bf(b.z); o[7] = f2bf(b.w);
    *(ushort8*)&dst[i] = o;
}

// ---------------------------------------------------------------------------
// bf16 MFMA GEMM, r10 config (128x128, 4 waves, 2-barrier, gl_lds staging).
// ---------------------------------------------------------------------------
template<int BM, int BN, int NWM, int NWN, bool BF16OUT>
__global__ __launch_bounds__(NWM * NWN * 64) void gemm_bf16_nt(
    const ushort_t* __restrict__ A,
    const ushort_t* __restrict__ B0, const ushort_t* __restrict__ B1,
    const ushort_t* __restrict__ B2,
    void* __restrict__ C0, void* __restrict__ C1, void* __restrict__ C2,
    int M, int N, int K) {
    constexpr int NT = NWM * NWN * 64;
    constexpr int WM = BM / NWM;
    constexpr int WN = BN / NWN;
    constexpr int MF = WM / 16, NF = WN / 16;
    constexpr int CA = BM * 8 / NT;
    constexpr int CB = BN * 8 / NT;
    constexpr int RPC = NT / 8;

    __shared__ ushort_t As[BM * 64];
    __shared__ ushort_t Bs[BN * 64];

    const int z = blockIdx.z;
    const ushort_t* B = (z == 0) ? B0 : (z == 1) ? B1 : B2;
    void* Cv          = (z == 0) ? C0 : (z == 1) ? C1 : C2;

    const int tid = threadIdx.x;
    const int w = tid >> 6;
    const int l = tid & 63;
    const int wr = w / NWN, wc = w % NWN;
    const int l16 = l & 15, g4 = l >> 4;
    const int row0 = blockIdx.y * BM;
    const int col0 = blockIdx.x * BN;

    const int srow = tid >> 3;
    const int scol = (tid & 7) * 8;
    const ushort_t* ga = A + (size_t)(row0 + srow) * K + scol;
    const ushort_t* gb = B + (size_t)(col0 + srow) * K + scol;
    ushort_t* lA = &As[w * 512];
    ushort_t* lB = &Bs[w * 512];

    f32x4 acc[MF][NF];
#pragma unroll
    for (int m = 0; m < MF; ++m)
#pragma unroll
        for (int n = 0; n < NF; ++n)
            acc[m][n] = (f32x4){0.0f, 0.0f, 0.0f, 0.0f};

    for (int k0 = 0; k0 < K; k0 += 64) {
        __syncthreads();
#pragma unroll
        for (int i = 0; i < CA; ++i)
            gl_lds16(ga + (size_t)i * RPC * K + k0, lA + i * NT * 8);
#pragma unroll
        for (int i = 0; i < CB; ++i)
            gl_lds16(gb + (size_t)i * RPC * K + k0, lB + i * NT * 8);
        __syncthreads();
#pragma unroll
        for (int kk = 0; kk < 2; ++kk) {
            short8 af[MF], bfr[NF];
#pragma unroll
            for (int m = 0; m < MF; ++m)
                af[m] = *(const short8*)&As[(wr * WM + m * 16 + l16) * 64 + kk * 32 + g4 * 8];
#pragma unroll
            for (int n = 0; n < NF; ++n)
                bfr[n] = *(const short8*)&Bs[(wc * WN + n * 16 + l16) * 64 + kk * 32 + g4 * 8];
#pragma unroll
            for (int m = 0; m < MF; ++m)
#pragma unroll
                for (int n = 0; n < NF; ++n)
                    acc[m][n] = __builtin_amdgcn_mfma_f32_16x16x32_bf16(af[m], bfr[n], acc[m][n], 0, 0, 0);
        }
    }

#pragma unroll
    for (int m = 0; m < MF; ++m) {
        const int grow = row0 + wr * WM + m * 16 + g4 * 4;
#pragma unroll
        for (int n = 0; n < NF; ++n) {
            const int gcol = col0 + wc * WN + n * 16 + l16;
#pragma unroll
            for (int r = 0; r < 4; ++r) {
                if (BF16OUT)
                    ((ushort_t*)Cv)[(size_t)(grow + r) * N + gcol] = f2bf(acc[m][n][r]);
                else
                    ((float*)Cv)[(size_t)(grow + r) * N + gcol] = acc[m][n][r];
            }
        }
    }
}

// ---------------------------------------------------------------------------
// In-place on bf16 q,k,v: v-blend, rmsnorm, rope. kb AND vb stored with the
// per-row 16B-chunk XOR swizzle (chunk c -> c ^ (t&7)).
// ---------------------------------------------------------------------------
__global__ __launch_bounds__(256) void norm_rope(ushort_t* __restrict__ qb,
                                                 ushort_t* __restrict__ kb,
                                                 ushort_t* __restrict__ vb,
                                                 const float* __restrict__ vi,
                                                 const float* __restrict__ lamb) {
    const int w = threadIdx.x >> 6;
    const int lane = threadIdx.x & 63;
    const int t = blockIdx.x;
    const int h = blockIdx.y * 4 + w;
    const size_t idx = (size_t)t * D_MODEL + h * HD + lane;

    const float lam = lamb[0];
    float qv = bf2f(qb[idx]);
    float kv = bf2f(kb[idx]);
    float vv = (1.0f - lam) * bf2f(vb[idx]) + lam * vi[idx];
    const int scol = ((((lane >> 3) ^ (t & 7)) << 3) | (lane & 7));
    vb[(size_t)t * D_MODEL + h * HD + scol] = f2bf(vv);

    float sq = qv * qv;
    float sk = kv * kv;
#pragma unroll
    for (int m = 1; m <= 32; m <<= 1) {
        sq += __shfl_xor(sq, m, 64);
        sk += __shfl_xor(sk, m, 64);
    }
    const float rq = rsqrtf(sq * (1.0f / 64.0f) + RMS_EPS);
    const float rk = rsqrtf(sk * (1.0f / 64.0f) + RMS_EPS);
    float qn = qv * rq;
    float kn = kv * rk;

    const int i = lane & 31;
    const float inv = exp2f(-0.4152410118609203f * (float)i);
    const float ang = (float)t * inv;
    float c, s;
    sincosf(ang, &s, &c);
    float qp = __shfl_xor(qn, 32, 64);
    float kp = __shfl_xor(kn, 32, 64);
    float qo, ko;
    if (lane < 32) {
        qo = qn * c + qp * s;
        ko = kn * c + kp * s;
    } else {
        qo = qn * c - qp * s;
        ko = kn * c - kp * s;
    }
    qb[idx] = f2bf(qo);
    kb[(size_t)t * D_MODEL + h * HD + scol] = f2bf(ko);
}

// ---------------------------------------------------------------------------
// Flash attention v7: QBLK=128 (wave owns 32 q-rows, 2 col-groups), KVBLK=64.
// DMA (K+V via global_load_lds, dbuf LDS) issued at the EARLIEST legal point
// -- right after barrierA -- so QK^T + softmax + Vt-write (~2x compute vs
// r12's PV-only) hides the L2/L3 latency before barrierB's implicit drain.
// Halves iteration/barrier count vs r12. Split-K for qt>=8.
// Grid = 384: b<256 split halves (qt=15-(b>>5), h=(b&31)>>1, half=b&1);
// b>=256 full units (qt=7-((b-256)>>4), h=(b-256)&15).
// ---------------------------------------------------------------------------
__global__ __launch_bounds__(256, 2) void attn_mfma(const ushort_t* __restrict__ qb,
                                                    const ushort_t* __restrict__ kb,
                                                    const ushort_t* __restrict__ vb,
                                                    const float* __restrict__ sink,
                                                    ushort_t* __restrict__ yb,
                                                    float* __restrict__ part_acc,
                                                    float* __restrict__ part_ml) {
    const int b = blockIdx.x;
    int h, qt, kt0, kt1, mode;   // mode 0 = full->y, 1/2 = partial half 0/1
    if (b < 256) {
        qt = 15 - (b >> 5);                 // 15..8
        const int rem = b & 31;
        h = rem >> 1;
        const int half = rem & 1;
        const int ntk = 2 * qt + 2;
        const int mid = ntk >> 1;           // qt+1
        kt0 = half ? mid : 0;
        kt1 = half ? ntk : mid;
        mode = 1 + half;
    } else {
        const int rem = b - 256;
        qt = 7 - (rem >> 4);                // 7..0
        h = rem & 15;
        kt0 = 0; kt1 = 2 * qt + 2; mode = 0;
    }

    __shared__ ushort_t Kl[2][64 * 64];     // K tiles (swizzled rows), dbuf
    __shared__ ushort_t Vl[2][64 * 64];     // V tiles (swizzled rows), dbuf
    __shared__ ushort_t Vt[64][72];         // V transposed (single buffer)
    __shared__ ushort_t Pl[4][32][72];      // per-wave P (32 q-rows)

    const int tid  = threadIdx.x;
    const int w    = tid >> 6;
    const int lane = tid & 63;
    const int l16  = lane & 15;
    const int g4   = lane >> 4;

    // Q B-frags: 2 col-groups x 2 k-chunks
    short8 q[2][2];
#pragma unroll
    for (int qg = 0; qg < 2; ++qg) {
        const size_t qoff = (size_t)(qt * 128 + w * 32 + qg * 16 + l16) * D_MODEL + h * HD;
        q[qg][0] = *(const short8*)&qb[qoff + 8 * g4];
        q[qg][1] = *(const short8*)&qb[qoff + 32 + 8 * g4];
    }

    // DMA staging geometry (wave w stages rows w*16..+15, 2 calls of 8 rows)
    const int srow_l = w * 16 + (lane >> 3);
    const int scol_l = (lane & 7) * 8;

    // prologue: DMA K,V tile kt0
#pragma unroll
    for (int i = 0; i < 2; ++i) {
        gl_lds16(kb + ((size_t)(kt0 * 64 + srow_l + i * 8) << 10) + h * HD + scol_l,
                 &Kl[kt0 & 1][w * 1024 + i * 512]);
        gl_lds16(vb + ((size_t)(kt0 * 64 + srow_l + i * 8) << 10) + h * HD + scol_l,
                 &Vl[kt0 & 1][w * 1024 + i * 512]);
    }

    float m[2]    = {-INFINITY, -INFINITY};
    float lsum[2] = {0.0f, 0.0f};
    f32x4 acc[2][4];
#pragma unroll
    for (int qg = 0; qg < 2; ++qg)
#pragma unroll
        for (int d = 0; d < 4; ++d) acc[qg][d] = (f32x4){0.0f, 0.0f, 0.0f, 0.0f};

    for (int kt = kt0; kt < kt1; ++kt) {
        const int cur = kt & 1;

        __syncthreads();   // barrierA: DMA[cur] drained; prev PV/Vt reads done

        // earliest legal DMA issue: buffer [cur^1]'s readers all pre-barrierA
        if (kt + 1 < kt1) {
            const int nxt = cur ^ 1;
#pragma unroll
            for (int i = 0; i < 2; ++i) {
                gl_lds16(kb + ((size_t)((kt + 1) * 64 + srow_l + i * 8) << 10) + h * HD + scol_l,
                         &Kl[nxt][w * 1024 + i * 512]);
                gl_lds16(vb + ((size_t)((kt + 1) * 64 + srow_l + i * 8) << 10) + h * HD + scol_l,
                         &Vl[nxt][w * 1024 + i * 512]);
            }
        }

        // V rows from Vl[cur] (chunk c at pos c^(row&7); row=lane)
        const ushort8 va0 = *(const ushort8*)&Vl[cur][lane * 64 + (((2 * w) ^ (lane & 7)) << 3)];
        const ushort8 va1 = *(const ushort8*)&Vl[cur][lane * 64 + (((2 * w + 1) ^ (lane & 7)) << 3)];

        // ---- QK^T: sf[qg][s][r] = S[key=s*16+g4*4+r][q-col=l16] ----
        f32x4 sf[2][4];
#pragma unroll
        for (int s = 0; s < 4; ++s) {
            const int row = s * 16 + l16;
            const int swz = l16 & 7;
            const short8 ka0 = *(const short8*)&Kl[cur][row * 64 + ((g4 ^ swz) << 3)];
            const short8 ka1 = *(const short8*)&Kl[cur][row * 64 + (((g4 + 4) ^ swz) << 3)];
#pragma unroll
            for (int qg = 0; qg < 2; ++qg) {
                f32x4 t = (f32x4){0.0f, 0.0f, 0.0f, 0.0f};
                t = __builtin_amdgcn_mfma_f32_16x16x32_bf16(ka0, q[qg][0], t, 0, 0, 0);
                t = __builtin_amdgcn_mfma_f32_16x16x32_bf16(ka1, q[qg][1], t, 0, 0, 0);
                sf[qg][s] = t;
            }
        }

        // stage V transpose (single Vt buffer; visible after barrierB)
#pragma unroll
        for (int j = 0; j < 8; ++j) {
            Vt[w * 16 + j][lane]     = va0[j];
            Vt[w * 16 + 8 + j][lane] = va1[j];
        }

        // ---- masking + row-max ----
        float mt[2] = {-INFINITY, -INFINITY};
        if (kt >= 2 * qt) {   // diagonal region (only last two key tiles)
#pragma unroll
            for (int qg = 0; qg < 2; ++qg) {
                const int qglob = qt * 128 + w * 32 + qg * 16 + l16;
#pragma unroll
                for (int s = 0; s < 4; ++s)
#pragma unroll
                    for (int r = 0; r < 4; ++r) {
                        const float sc = sf[qg][s][r] * 0.125f;
                        const int kglob = kt * 64 + s * 16 + g4 * 4 + r;
                        sf[qg][s][r] = (kglob > qglob) ? -INFINITY : sc;
                        mt[qg] = fmaxf(mt[qg], sf[qg][s][r]);
                    }
            }
        } else {
#pragma unroll
            for (int qg = 0; qg < 2; ++qg)
#pragma unroll
                for (int s = 0; s < 4; ++s)
#pragma unroll
                    for (int r = 0; r < 4; ++r) {
                        sf[qg][s][r] *= 0.125f;
                        mt[qg] = fmaxf(mt[qg], sf[qg][s][r]);
                    }
        }
#pragma unroll
        for (int qg = 0; qg < 2; ++qg) {
            mt[qg] = fmaxf(mt[qg], __shfl_xor(mt[qg], 16, 64));
            mt[qg] = fmaxf(mt[qg], __shfl_xor(mt[qg], 32, 64));
        }

        float corr[2];
#pragma unroll
        for (int qg = 0; qg < 2; ++qg) {
            const float mnew = fmaxf(m[qg], mt[qg]);
            corr[qg] = __expf(m[qg] - mnew);
            m[qg] = mnew;

            float ps = 0.0f;
#pragma unroll
            for (int s = 0; s < 4; ++s) {
                const float e0 = __expf(sf[qg][s][0] - m[qg]);
                const float e1 = __expf(sf[qg][s][1] - m[qg]);
                const float e2 = __expf(sf[qg][s][2] - m[qg]);
                const float e3 = __expf(sf[qg][s][3] - m[qg]);
                ps += (e0 + e1) + (e2 + e3);
                uint2 pk;
                pk.x = cvt_pk_bf16(e0, e1);
                pk.y = cvt_pk_bf16(e2, e3);
                *(uint2*)&Pl[w][qg * 16 + l16][s * 16 + g4 * 4] = pk;
            }
            ps += __shfl_xor(ps, 16, 64);
            ps += __shfl_xor(ps, 32, 64);
            lsum[qg] = lsum[qg] * corr[qg] + ps;
        }

        // acc rescale (register-only; before barrier to shorten post-phase)
#pragma unroll
        for (int qg = 0; qg < 2; ++qg) {
            float corrq[4];
#pragma unroll
            for (int r = 0; r < 4; ++r) corrq[r] = __shfl(corr[qg], g4 * 4 + r, 64);
#pragma unroll
            for (int d = 0; d < 4; ++d)
#pragma unroll
                for (int r = 0; r < 4; ++r) acc[qg][d][r] *= corrq[r];
        }

        __syncthreads();   // barrierB: Vt + Pl visible (drains DMA[nxt] too)

        // ---- PV: 16 MFMA; V frags shared across qg ----
        short8 pa[2][2];
#pragma unroll
        for (int qg = 0; qg < 2; ++qg) {
            pa[qg][0] = *(const short8*)&Pl[w][qg * 16 + l16][8 * g4];
            pa[qg][1] = *(const short8*)&Pl[w][qg * 16 + l16][32 + 8 * g4];
        }
#pragma unroll
        for (int d = 0; d < 4; ++d) {
            const short8 v0 = *(const short8*)&Vt[d * 16 + l16][8 * g4];
            const short8 v1 = *(const short8*)&Vt[d * 16 + l16][32 + 8 * g4];
#pragma unroll
            for (int qg = 0; qg < 2; ++qg) {
                acc[qg][d] = __builtin_amdgcn_mfma_f32_16x16x32_bf16(pa[qg][0], v0, acc[qg][d], 0, 0, 0);
                acc[qg][d] = __builtin_amdgcn_mfma_f32_16x16x32_bf16(pa[qg][1], v1, acc[qg][d], 0, 0, 0);
            }
        }
    }

    if (mode == 0) {
#pragma unroll
        for (int qg = 0; qg < 2; ++qg) {
            const float lse = m[qg] + __logf(lsum[qg]);
            const float scale = 1.0f / (1.0f + __expf(-(lse - sink[h])));
            const float fv = scale / lsum[qg];
            float fq[4];
#pragma unroll
            for (int r = 0; r < 4; ++r) fq[r] = __shfl(fv, g4 * 4 + r, 64);
#pragma unroll
            for (int r = 0; r < 4; ++r) {
                const size_t yoff = (size_t)(qt * 128 + w * 32 + qg * 16 + g4 * 4 + r) * D_MODEL + h * HD + l16;
#pragma unroll
                for (int d = 0; d < 4; ++d)
                    yb[yoff + d * 16] = f2bf(acc[qg][d][r] * fq[r]);
            }
        }
    } else {
        const int pi = ((qt - 8) * 16 + h) * 2 + (mode - 1);
        if (g4 == 0) {
            float* ml = part_ml + (size_t)pi * 256;
#pragma unroll
            for (int qg = 0; qg < 2; ++qg) {
                ml[w * 32 + qg * 16 + l16]       = m[qg];
                ml[128 + w * 32 + qg * 16 + l16] = lsum[qg];
            }
        }
        float* pa = part_acc + (size_t)pi * 8192;
#pragma unroll
        for (int qg = 0; qg < 2; ++qg)
#pragma unroll
            for (int r = 0; r < 4; ++r) {
                const int row = w * 32 + qg * 16 + g4 * 4 + r;
#pragma unroll
                for (int d = 0; d < 4; ++d)
                    pa[row * 64 + d * 16 + l16] = acc[qg][d][r];
            }
    }
}

// ---------------------------------------------------------------------------
// Merge the two key-half partials for qt>=8 (128-row units) + sink scaling.
// Block = one (qt,h) unit; 512 work items (row, 16-col group), 2 per thread.
// ---------------------------------------------------------------------------
__global__ __launch_bounds__(256) void attn_combine(const float* __restrict__ part_acc,
                                                    const float* __restrict__ part_ml,
                                                    const float* __restrict__ sink,
                                                    ushort_t* __restrict__ yb) {
    const int si = blockIdx.x;          // (qt-8)*16 + h
    const int h  = si & 15;
    const int qt = 8 + (si >> 4);
    const float sw = sink[h];

#pragma unroll
    for (int ii = 0; ii < 2; ++ii) {
        const int idx = threadIdx.x + ii * 256;   // 0..511
        const int row = idx >> 2;
        const int c0  = (idx & 3) * 16;

        const float* a0 = part_acc + ((size_t)si * 2) * 8192 + row * 64 + c0;
        const float* a1 = a0 + 8192;
        const float* ml = part_ml + (size_t)si * 2 * 256;
        const float m0 = ml[row],       l0 = ml[128 + row];
        const float m1 = ml[256 + row], l1 = ml[384 + row];
        const float M  = fmaxf(m0, m1);
        const float e0 = __expf(m0 - M), e1 = __expf(m1 - M);
        const float l  = l0 * e0 + l1 * e1;
        const float lse = M + __logf(l);
        const float scale = 1.0f / (1.0f + __expf(-(lse - sw)));
        const float f = scale / l;

        ushort8 o[2];
#pragma unroll
        for (int j = 0; j < 16; ++j) {
            const float v = (a0[j] * e0 + a1[j] * e1) * f;
            o[j >> 3][j & 7] = f2bf(v);
        }
        ushort_t* yp = yb + (size_t)(qt * 128 + row) * D_MODEL + h * HD + c0;
        *(ushort8*)yp       = o[0];
        *(ushort8*)(yp + 8) = o[1];
    }
}

// ---------------------------------------------------------------------------
extern "C" void kernel_launch(void* const* d_in, const int* in_sizes, int n_in,
                              void* d_out, int out_size, void* d_ws, size_t ws_size,
                              hipStream_t stream) {
    const float* x    = (const float*)d_in[0];
    const float* vi   = (const float*)d_in[1];
    const float* Wq   = (const float*)d_in[2];
    const float* Wk   = (const float*)d_in[3];
    const float* Wv   = (const float*)d_in[4];
    const float* Wo   = (const float*)d_in[5];
    const float* lamb = (const float*)d_in[6];
    const float* sink = (const float*)d_in[7];
    float* out = (float*)d_out;

    const size_t TD = (size_t)T_SEQ * D_MODEL;    // 2M elts
    const size_t WD = (size_t)D_MODEL * D_MODEL;  // 1M elts
    ushort_t* qbuf = (ushort_t*)d_ws;             // [ 0, 4)MB
    ushort_t* kbuf = qbuf + TD;                   // [ 4, 8)MB
    ushort_t* vbuf = kbuf + TD;                   // [ 8,12)MB
    ushort_t* yb   = vbuf + TD;                   // [12,16)MB
    ushort_t* wob  = yb + TD;                     // [16,18)MB
    ushort_t* xb   = wob + WD;                    // [18,22)MB
    ushort_t* wqb  = xb + TD;                     // [22,24)MB
    ushort_t* wkb  = wqb + WD;                    // [24,26)MB
    ushort_t* wvb  = wkb + WD;                    // [26,28)MB
    // attn partials overlay the staging buffers (dead after the QKV GEMM):
    float* part_acc = (float*)xb;                 // 8 MB  [18,26)MB
    float* part_ml  = (float*)wvb;                // 256 KB in [26,28)MB

    cast_to_bf16<<<dim3(512, 6), 256, 0, stream>>>(x, Wq, Wk, Wv, Wo,
                                                   xb, wqb, wkb, wvb, wob);

    gemm_bf16_nt<128, 128, 2, 2, true>
        <<<dim3(D_MODEL / 128, T_SEQ / 128, 3), 256, 0, stream>>>(
        xb, wqb, wkb, wvb, qbuf, kbuf, vbuf, T_SEQ, D_MODEL, D_MODEL);

    norm_rope<<<dim3(T_SEQ, NH / 4), 256, 0, stream>>>(qbuf, kbuf, vbuf, vi, lamb);

    attn_mfma<<<dim3(384), 256, 0, stream>>>(qbuf, kbuf, vbuf, sink, yb,
                                             part_acc, part_ml);
    attn_combine<<<dim3(128), 256, 0, stream>>>(part_acc, part_ml, sink, yb);

    gemm_bf16_nt<128, 128, 2, 2, false>
        <<<dim3(D_MODEL / 128, T_SEQ / 128, 1), 256, 0, stream>>>(
        yb, wob, wob, wob, out, out, out, T_SEQ, D_MODEL, D_MODEL);
}

// Round 15
// 100.678 us; speedup vs baseline: 1.1390x; 1.1390x over previous
//
#include <hip/hip_runtime.h>
#include <math.h>

#define T_SEQ 2048
#define D_MODEL 1024
#define NH 16
#define HD 64
#define RMS_EPS 1.1920928955078125e-07f

typedef unsigned short ushort_t;
typedef __attribute__((ext_vector_type(8))) short short8;
typedef __attribute__((ext_vector_type(8))) unsigned short ushort8;
typedef __attribute__((ext_vector_type(4))) float f32x4;

static __device__ __forceinline__ unsigned short f2bf(float f) {
    union { float f; unsigned u; } v; v.f = f;
    unsigned r = v.u + 0x7fff + ((v.u >> 16) & 1);   // RNE
    return (unsigned short)(r >> 16);
}
static __device__ __forceinline__ unsigned cvt_pk_bf16(float lo, float hi) {
    unsigned r;
    asm("v_cvt_pk_bf16_f32 %0, %1, %2" : "=v"(r) : "v"(lo), "v"(hi));
    return r;
}
static __device__ __forceinline__ void gl_lds16(const ushort_t* g, ushort_t* l) {
    __builtin_amdgcn_global_load_lds(
        (const __attribute__((address_space(1))) unsigned int*)g,
        (__attribute__((address_space(3))) unsigned int*)l, 16, 0, 0);
}

// ---------------------------------------------------------------------------
// Cast f32 -> bf16: x (2M elements, segs 0-1) and the 4 weights (1M each).
// ---------------------------------------------------------------------------
__global__ __launch_bounds__(256) void cast_to_bf16(
    const float* __restrict__ x, const float* __restrict__ wq,
    const float* __restrict__ wk, const float* __restrict__ wv,
    const float* __restrict__ wo,
    ushort_t* __restrict__ xb, ushort_t* __restrict__ wqb,
    ushort_t* __restrict__ wkb, ushort_t* __restrict__ wvb,
    ushort_t* __restrict__ wob) {
    const int seg = blockIdx.y;
    const float* src; ushort_t* dst; size_t base = 0;
    if (seg == 0)      { src = x;  dst = xb; }
    else if (seg == 1) { src = x;  dst = xb; base = 1u << 20; }
    else if (seg == 2) { src = wq; dst = wqb; }
    else if (seg == 3) { src = wk; dst = wkb; }
    else if (seg == 4) { src = wv; dst = wvb; }
    else               { src = wo; dst = wob; }
    const size_t i = base + ((size_t)blockIdx.x * 256 + threadIdx.x) * 8;
    float4 a = *(const float4*)&src[i];
    float4 b = *(const float4*)&src[i + 4];
    ushort8 o;
    o[0] = f2bf(a.x); o[1] = f2bf(a.y); o[2] = f2bf(a.z); o[3] = f2bf(a.w);
    o[4] = f2bf(b.x); o[5] = f2bf(b.y); o[6] = f2bf(b.z); o[7] = f2bf(b.w);
    *(ushort8*)&dst[i] = o;
}

// ---------------------------------------------------------------------------
// bf16 MFMA GEMM, r10 config (128x128, 4 waves 2x2, 2-barrier, gl_lds).
// MODE 0: plain f32 store (Wo).
// MODE 1: fused QKV epilogue. The wave's 64-col sub-tile = one full head
//   (h = 2*blockIdx.x + wc), so:
//   z=0 (q): RMS(16-lane shfl reduce) + RoPE(frag n<->n+2 register-local),
//            linear bf16 store.
//   z=1 (k): same + per-row chunk-XOR swizzled store (attn LDS pre-swizzle).
//   z=2 (v): blend with vi, linear bf16 store.
//   Replaces the norm_rope kernel + q/k/v global round-trip.
// ---------------------------------------------------------------------------
template<int MODE>
__global__ __launch_bounds__(256) void gemm_bf16_nt(
    const ushort_t* __restrict__ A,
    const ushort_t* __restrict__ B0, const ushort_t* __restrict__ B1,
    const ushort_t* __restrict__ B2,
    void* __restrict__ C0, void* __restrict__ C1, void* __restrict__ C2,
    const float* __restrict__ vi, const float* __restrict__ lamb,
    int M, int N, int K) {
    __shared__ ushort_t As[128 * 64];
    __shared__ ushort_t Bs[128 * 64];

    const int z = blockIdx.z;
    const ushort_t* B = (z == 0) ? B0 : (z == 1) ? B1 : B2;
    void* Cv          = (z == 0) ? C0 : (z == 1) ? C1 : C2;

    const int tid = threadIdx.x;
    const int w = tid >> 6;
    const int l = tid & 63;
    const int wr = w >> 1, wc = w & 1;
    const int l16 = l & 15, g4 = l >> 4;
    const int row0 = blockIdx.y * 128;
    const int col0 = blockIdx.x * 128;

    const int srow = tid >> 3;
    const int scol = (tid & 7) * 8;
    const ushort_t* ga = A + (size_t)(row0 + srow) * K + scol;
    const ushort_t* gb = B + (size_t)(col0 + srow) * K + scol;
    ushort_t* lA = &As[w * 512];
    ushort_t* lB = &Bs[w * 512];

    f32x4 acc[4][4];
#pragma unroll
    for (int m = 0; m < 4; ++m)
#pragma unroll
        for (int n = 0; n < 4; ++n)
            acc[m][n] = (f32x4){0.0f, 0.0f, 0.0f, 0.0f};

    for (int k0 = 0; k0 < K; k0 += 64) {
        __syncthreads();
#pragma unroll
        for (int i = 0; i < 4; ++i) {
            gl_lds16(ga + (size_t)i * 32 * K + k0, lA + i * 2048);
            gl_lds16(gb + (size_t)i * 32 * K + k0, lB + i * 2048);
        }
        __syncthreads();
#pragma unroll
        for (int kk = 0; kk < 2; ++kk) {
            short8 af[4], bfr[4];
#pragma unroll
            for (int m = 0; m < 4; ++m)
                af[m] = *(const short8*)&As[(wr * 64 + m * 16 + l16) * 64 + kk * 32 + g4 * 8];
#pragma unroll
            for (int n = 0; n < 4; ++n)
                bfr[n] = *(const short8*)&Bs[(wc * 64 + n * 16 + l16) * 64 + kk * 32 + g4 * 8];
#pragma unroll
            for (int m = 0; m < 4; ++m)
#pragma unroll
                for (int n = 0; n < 4; ++n)
                    acc[m][n] = __builtin_amdgcn_mfma_f32_16x16x32_bf16(af[m], bfr[n], acc[m][n], 0, 0, 0);
        }
    }

    if (MODE == 0) {
#pragma unroll
        for (int m = 0; m < 4; ++m) {
            const int grow = row0 + wr * 64 + m * 16 + g4 * 4;
#pragma unroll
            for (int n = 0; n < 4; ++n) {
                const int gcol = col0 + wc * 64 + n * 16 + l16;
#pragma unroll
                for (int r = 0; r < 4; ++r)
                    ((float*)Cv)[(size_t)(grow + r) * N + gcol] = acc[m][n][r];
            }
        }
    } else {
        const int hh = 2 * blockIdx.x + wc;   // this wave's head
        if (z == 2) {
            const float lam = lamb[0];
#pragma unroll
            for (int m = 0; m < 4; ++m)
#pragma unroll
                for (int r = 0; r < 4; ++r) {
                    const int row = row0 + wr * 64 + m * 16 + g4 * 4 + r;
#pragma unroll
                    for (int n = 0; n < 4; ++n) {
                        const int d = n * 16 + l16;
                        const float vv = (1.0f - lam) * acc[m][n][r]
                                       + lam * vi[(size_t)row * D_MODEL + hh * HD + d];
                        ((ushort_t*)Cv)[(size_t)row * D_MODEL + hh * HD + d] = f2bf(vv);
                    }
                }
        } else {
#pragma unroll
            for (int m = 0; m < 4; ++m)
#pragma unroll
                for (int r = 0; r < 4; ++r) {
                    const int row = row0 + wr * 64 + m * 16 + g4 * 4 + r;
                    // RMS over the 64-dim head: per-lane partial, 16-lane reduce
                    float s = acc[m][0][r] * acc[m][0][r] + acc[m][1][r] * acc[m][1][r]
                            + acc[m][2][r] * acc[m][2][r] + acc[m][3][r] * acc[m][3][r];
                    s += __shfl_xor(s, 1, 64);
                    s += __shfl_xor(s, 2, 64);
                    s += __shfl_xor(s, 4, 64);
                    s += __shfl_xor(s, 8, 64);
                    const float rq = rsqrtf(s * (1.0f / 64.0f) + RMS_EPS);
                    float a[4];
#pragma unroll
                    for (int n = 0; n < 4; ++n) a[n] = acc[m][n][r] * rq;
                    // RoPE: pair (d, d+32) = frag n and n+2 (register-local)
#pragma unroll
                    for (int n = 0; n < 2; ++n) {
                        const int i = n * 16 + l16;
                        const float inv = exp2f(-0.4152410118609203f * (float)i);
                        float sn, c;
                        sincosf((float)row * inv, &sn, &c);
                        const float a0 = a[n], a2 = a[n + 2];
                        a[n]     = a0 * c + a2 * sn;
                        a[n + 2] = -a0 * sn + a2 * c;
                    }
#pragma unroll
                    for (int n = 0; n < 4; ++n) {
                        const int d = n * 16 + l16;
                        int col;
                        if (z == 1)   // swizzled K store (chunk ^ row&7)
                            col = hh * HD + ((((d >> 3) ^ (row & 7)) << 3) | (d & 7));
                        else          // linear Q store
                            col = hh * HD + d;
                        ((ushort_t*)Cv)[(size_t)row * D_MODEL + col] = f2bf(a[n]);
                    }
                }
        }
    }
}

// ---------------------------------------------------------------------------
// Flash attention v5 (r10 verbatim -- best measured: 41.3us): K tiles via
// global_load_lds dbuf LDS (swizzled), V reg-prefetch, split-K, swapped
// QK^T, cvt_pk P-stores.
// ---------------------------------------------------------------------------
__global__ __launch_bounds__(256, 2) void attn_mfma(const ushort_t* __restrict__ qb,
                                                    const ushort_t* __restrict__ kb,
                                                    const ushort_t* __restrict__ vb,
                                                    const float* __restrict__ sink,
                                                    ushort_t* __restrict__ yb,
                                                    float* __restrict__ part_acc,
                                                    float* __restrict__ part_ml) {
    const int b = blockIdx.x;
    int h, qt, kt0, kt1, mode;   // mode 0 = full->y, 1/2 = partial half 0/1
    if (b < 512) {
        qt = 31 - (b >> 5);
        const int rem = b & 31;
        h = rem >> 1;
        const int half = rem & 1;
        const int mid = (qt + 1) >> 1;
        kt0 = half ? mid : 0;
        kt1 = half ? (qt + 1) : mid;
        mode = 1 + half;
    } else {
        const int rem = b - 512;
        qt = 15 - (rem >> 4);
        h = rem & 15;
        kt0 = 0; kt1 = qt + 1; mode = 0;
    }

    __shared__ ushort_t Kl[2][64 * 64];     // K tiles (swizzled rows), dbuf
    __shared__ ushort_t Vt[2][64][72];      // V transposed, dbuf
    __shared__ ushort_t Pl[4][16][72];      // per-wave P

    const int tid  = threadIdx.x;
    const int w    = tid >> 6;
    const int lane = tid & 63;
    const int l16  = lane & 15;
    const int g4   = lane >> 4;

    const size_t qoff = (size_t)(qt * 64 + w * 16 + l16) * D_MODEL + h * HD;
    const short8 q0 = *(const short8*)&qb[qoff + 8 * g4];
    const short8 q1 = *(const short8*)&qb[qoff + 32 + 8 * g4];

    const int krow_l = w * 16 + (lane >> 3);
    const int kcol_l = (lane & 7) * 8;

#pragma unroll
    for (int i = 0; i < 2; ++i)
        gl_lds16(kb + ((size_t)(kt0 * 64 + krow_l + i * 8) << 10) + h * HD + kcol_l,
                 &Kl[kt0 & 1][w * 1024 + i * 512]);
    ushort8 va0, va1;
    {
        const size_t voff = (size_t)(kt0 * 64 + lane) * D_MODEL + h * HD + w * 16;
        va0 = *(const ushort8*)&vb[voff];
        va1 = *(const ushort8*)&vb[voff + 8];
    }

    float m = -INFINITY, lsum = 0.0f;
    f32x4 acc[4];
#pragma unroll
    for (int d = 0; d < 4; ++d) acc[d] = (f32x4){0.0f, 0.0f, 0.0f, 0.0f};

    for (int kt = kt0; kt < kt1; ++kt) {
        const int cur = kt & 1;

#pragma unroll
        for (int j = 0; j < 8; ++j) {
            Vt[cur][w * 16 + j][lane]     = va0[j];
            Vt[cur][w * 16 + 8 + j][lane] = va1[j];
        }

        __syncthreads();   // drains K DMA for [cur]; orders Vt[cur]; frees [cur^1]

        ushort8 vn0, vn1;
        if (kt + 1 < kt1) {
#pragma unroll
            for (int i = 0; i < 2; ++i)
                gl_lds16(kb + ((size_t)((kt + 1) * 64 + krow_l + i * 8) << 10) + h * HD + kcol_l,
                         &Kl[cur ^ 1][w * 1024 + i * 512]);
            const size_t voff = (size_t)((kt + 1) * 64 + lane) * D_MODEL + h * HD + w * 16;
            vn0 = *(const ushort8*)&vb[voff];
            vn1 = *(const ushort8*)&vb[voff + 8];
        }

        f32x4 sf[4];
#pragma unroll
        for (int s = 0; s < 4; ++s) {
            const int row = s * 16 + l16;
            const int swz = l16 & 7;
            const short8 ka0 = *(const short8*)&Kl[cur][row * 64 + ((g4 ^ swz) << 3)];
            const short8 ka1 = *(const short8*)&Kl[cur][row * 64 + (((g4 + 4) ^ swz) << 3)];
            f32x4 t = (f32x4){0.0f, 0.0f, 0.0f, 0.0f};
            t = __builtin_amdgcn_mfma_f32_16x16x32_bf16(ka0, q0, t, 0, 0, 0);
            t = __builtin_amdgcn_mfma_f32_16x16x32_bf16(ka1, q1, t, 0, 0, 0);
            sf[s] = t;
        }

        float mt = -INFINITY;
        if (kt == qt) {
            const int ql = w * 16 + l16;
#pragma unroll
            for (int s = 0; s < 4; ++s)
#pragma unroll
                for (int r = 0; r < 4; ++r) {
                    const float sc = sf[s][r] * 0.125f;
                    sf[s][r] = (s * 16 + g4 * 4 + r > ql) ? -INFINITY : sc;
                    mt = fmaxf(mt, sf[s][r]);
                }
        } else {
#pragma unroll
            for (int s = 0; s < 4; ++s)
#pragma unroll
                for (int r = 0; r < 4; ++r) {
                    sf[s][r] *= 0.125f;
                    mt = fmaxf(mt, sf[s][r]);
                }
        }
        mt = fmaxf(mt, __shfl_xor(mt, 16, 64));
        mt = fmaxf(mt, __shfl_xor(mt, 32, 64));

        const float mnew = fmaxf(m, mt);
        const float corr = __expf(m - mnew);
        m = mnew;

        float ps = 0.0f;
#pragma unroll
        for (int s = 0; s < 4; ++s) {
            const float e0 = __expf(sf[s][0] - m);
            const float e1 = __expf(sf[s][1] - m);
            const float e2 = __expf(sf[s][2] - m);
            const float e3 = __expf(sf[s][3] - m);
            ps += (e0 + e1) + (e2 + e3);
            uint2 pk;
            pk.x = cvt_pk_bf16(e0, e1);
            pk.y = cvt_pk_bf16(e2, e3);
            *(uint2*)&Pl[w][l16][s * 16 + g4 * 4] = pk;
        }
        ps += __shfl_xor(ps, 16, 64);
        ps += __shfl_xor(ps, 32, 64);
        lsum = lsum * corr + ps;

        float corrq[4];
#pragma unroll
        for (int r = 0; r < 4; ++r) corrq[r] = __shfl(corr, g4 * 4 + r, 64);
#pragma unroll
        for (int d = 0; d < 4; ++d)
#pragma unroll
            for (int r = 0; r < 4; ++r) acc[d][r] *= corrq[r];

        const short8 pa0 = *(const short8*)&Pl[w][l16][8 * g4];
        const short8 pa1 = *(const short8*)&Pl[w][l16][32 + 8 * g4];
#pragma unroll
        for (int d = 0; d < 4; ++d) {
            const short8 v0 = *(const short8*)&Vt[cur][d * 16 + l16][8 * g4];
            const short8 v1 = *(const short8*)&Vt[cur][d * 16 + l16][32 + 8 * g4];
            acc[d] = __builtin_amdgcn_mfma_f32_16x16x32_bf16(pa0, v0, acc[d], 0, 0, 0);
            acc[d] = __builtin_amdgcn_mfma_f32_16x16x32_bf16(pa1, v1, acc[d], 0, 0, 0);
        }

        if (kt + 1 < kt1) { va0 = vn0; va1 = vn1; }
    }

    if (mode == 0) {
        const float lse = m + __logf(lsum);
        const float scale = 1.0f / (1.0f + __expf(-(lse - sink[h])));
        const float fv = scale / lsum;
        float fq[4];
#pragma unroll
        for (int r = 0; r < 4; ++r) fq[r] = __shfl(fv, g4 * 4 + r, 64);
#pragma unroll
        for (int r = 0; r < 4; ++r) {
            const size_t yoff = (size_t)(qt * 64 + w * 16 + g4 * 4 + r) * D_MODEL + h * HD + l16;
#pragma unroll
            for (int d = 0; d < 4; ++d)
                yb[yoff + d * 16] = f2bf(acc[d][r] * fq[r]);
        }
    } else {
        const int pi = ((qt - 16) * 16 + h) * 2 + (mode - 1);
        if (g4 == 0) {
            float* ml = part_ml + (size_t)pi * 128;
            ml[w * 16 + l16]      = m;
            ml[64 + w * 16 + l16] = lsum;
        }
        float* pa = part_acc + (size_t)pi * 4096;
#pragma unroll
        for (int r = 0; r < 4; ++r) {
            const int row = w * 16 + g4 * 4 + r;
#pragma unroll
            for (int d = 0; d < 4; ++d)
                pa[row * 64 + d * 16 + l16] = acc[d][r];
        }
    }
}

// ---------------------------------------------------------------------------
// Merge the two key-half partials for qt>=16 and apply sink scaling.
// ---------------------------------------------------------------------------
__global__ __launch_bounds__(256) void attn_combine(const float* __restrict__ part_acc,
                                                    const float* __restrict__ part_ml,
                                                    const float* __restrict__ sink,
                                                    ushort_t* __restrict__ yb) {
    const int si = blockIdx.x;          // (qt-16)*16 + h
    const int h  = si & 15;
    const int qt = 16 + (si >> 4);
    const int t  = threadIdx.x;
    const int row = t >> 2;
    const int c0  = (t & 3) * 16;

    const float* a0 = part_acc + ((size_t)si * 2) * 4096 + row * 64 + c0;
    const float* a1 = a0 + 4096;
    const float* ml = part_ml + (size_t)si * 2 * 128;
    const float m0 = ml[row],       l0 = ml[64 + row];
    const float m1 = ml[128 + row], l1 = ml[192 + row];
    const float M  = fmaxf(m0, m1);
    const float e0 = __expf(m0 - M), e1 = __expf(m1 - M);
    const float l  = l0 * e0 + l1 * e1;
    const float lse = M + __logf(l);
    const float scale = 1.0f / (1.0f + __expf(-(lse - sink[h])));
    const float f = scale / l;

    ushort8 o[2];
#pragma unroll
    for (int j = 0; j < 16; ++j) {
        const float v = (a0[j] * e0 + a1[j] * e1) * f;
        o[j >> 3][j & 7] = f2bf(v);
    }
    ushort_t* yp = yb + (size_t)(qt * 64 + row) * D_MODEL + h * HD + c0;
    *(ushort8*)yp       = o[0];
    *(ushort8*)(yp + 8) = o[1];
}

// ---------------------------------------------------------------------------
extern "C" void kernel_launch(void* const* d_in, const int* in_sizes, int n_in,
                              void* d_out, int out_size, void* d_ws, size_t ws_size,
                              hipStream_t stream) {
    const float* x    = (const float*)d_in[0];
    const float* vi   = (const float*)d_in[1];
    const float* Wq   = (const float*)d_in[2];
    const float* Wk   = (const float*)d_in[3];
    const float* Wv   = (const float*)d_in[4];
    const float* Wo   = (const float*)d_in[5];
    const float* lamb = (const float*)d_in[6];
    const float* sink = (const float*)d_in[7];
    float* out = (float*)d_out;

    const size_t TD = (size_t)T_SEQ * D_MODEL;    // 2M elts
    const size_t WD = (size_t)D_MODEL * D_MODEL;  // 1M elts
    ushort_t* qbuf = (ushort_t*)d_ws;             // [ 0, 4)MB
    ushort_t* kbuf = qbuf + TD;                   // [ 4, 8)MB
    ushort_t* vbuf = kbuf + TD;                   // [ 8,12)MB
    ushort_t* yb   = vbuf + TD;                   // [12,16)MB
    ushort_t* wob  = yb + TD;                     // [16,18)MB
    ushort_t* xb   = wob + WD;                    // [18,22)MB
    ushort_t* wqb  = xb + TD;                     // [22,24)MB
    ushort_t* wkb  = wqb + WD;                    // [24,26)MB
    ushort_t* wvb  = wkb + WD;                    // [26,28)MB
    // attn partials overlay the staging buffers (dead after the QKV GEMM):
    float* part_acc = (float*)xb;                 // 8 MB  [18,26)MB
    float* part_ml  = (float*)wvb;                // 256 KB in [26,28)MB

    cast_to_bf16<<<dim3(512, 6), 256, 0, stream>>>(x, Wq, Wk, Wv, Wo,
                                                   xb, wqb, wkb, wvb, wob);

    // fused QKV projection + v-blend + RMSNorm + RoPE (+K pre-swizzle)
    gemm_bf16_nt<1><<<dim3(D_MODEL / 128, T_SEQ / 128, 3), 256, 0, stream>>>(
        xb, wqb, wkb, wvb, qbuf, kbuf, vbuf, vi, lamb, T_SEQ, D_MODEL, D_MODEL);

    attn_mfma<<<dim3(768), 256, 0, stream>>>(qbuf, kbuf, vbuf, sink, yb,
                                             part_acc, part_ml);
    attn_combine<<<dim3(256), 256, 0, stream>>>(part_acc, part_ml, sink, yb);

    gemm_bf16_nt<0><<<dim3(D_MODEL / 128, T_SEQ / 128, 1), 256, 0, stream>>>(
        yb, wob, wob, wob, out, out, out, nullptr, nullptr, T_SEQ, D_MODEL, D_MODEL);
}

// Round 16
// 97.591 us; speedup vs baseline: 1.1750x; 1.0316x over previous
//
#include <hip/hip_runtime.h>
#include <math.h>

#define T_SEQ 2048
#define D_MODEL 1024
#define NH 16
#define HD 64
#define RMS_EPS 1.1920928955078125e-07f

typedef unsigned short ushort_t;
typedef __attribute__((ext_vector_type(8))) short short8;
typedef __attribute__((ext_vector_type(8))) unsigned short ushort8;
typedef __attribute__((ext_vector_type(4))) float f32x4;

static __device__ __forceinline__ unsigned short f2bf(float f) {
    union { float f; unsigned u; } v; v.f = f;
    unsigned r = v.u + 0x7fff + ((v.u >> 16) & 1);   // RNE
    return (unsigned short)(r >> 16);
}
static __device__ __forceinline__ unsigned cvt_pk_bf16(float lo, float hi) {
    unsigned r;
    asm("v_cvt_pk_bf16_f32 %0, %1, %2" : "=v"(r) : "v"(lo), "v"(hi));
    return r;
}
static __device__ __forceinline__ void gl_lds16(const ushort_t* g, ushort_t* l) {
    __builtin_amdgcn_global_load_lds(
        (const __attribute__((address_space(1))) unsigned int*)g,
        (__attribute__((address_space(3))) unsigned int*)l, 16, 0, 0);
}

// ---------------------------------------------------------------------------
// Cast f32 -> bf16: x (2M elements, segs 0-1) and the 4 weights (1M each).
// ---------------------------------------------------------------------------
__global__ __launch_bounds__(256) void cast_to_bf16(
    const float* __restrict__ x, const float* __restrict__ wq,
    const float* __restrict__ wk, const float* __restrict__ wv,
    const float* __restrict__ wo,
    ushort_t* __restrict__ xb, ushort_t* __restrict__ wqb,
    ushort_t* __restrict__ wkb, ushort_t* __restrict__ wvb,
    ushort_t* __restrict__ wob) {
    const int seg = blockIdx.y;
    const float* src; ushort_t* dst; size_t base = 0;
    if (seg == 0)      { src = x;  dst = xb; }
    else if (seg == 1) { src = x;  dst = xb; base = 1u << 20; }
    else if (seg == 2) { src = wq; dst = wqb; }
    else if (seg == 3) { src = wk; dst = wkb; }
    else if (seg == 4) { src = wv; dst = wvb; }
    else               { src = wo; dst = wob; }
    const size_t i = base + ((size_t)blockIdx.x * 256 + threadIdx.x) * 8;
    float4 a = *(const float4*)&src[i];
    float4 b = *(const float4*)&src[i + 4];
    ushort8 o;
    o[0] = f2bf(a.x); o[1] = f2bf(a.y); o[2] = f2bf(a.z); o[3] = f2bf(a.w);
    o[4] = f2bf(b.x); o[5] = f2bf(b.y); o[6] = f2bf(b.z); o[7] = f2bf(b.w);
    *(ushort8*)&dst[i] = o;
}

// ---------------------------------------------------------------------------
// bf16 MFMA GEMM, r10 config. MODE 0: f32 store (Wo). MODE 1: fused QKV:
//   z=0 (q): RMS + RoPE, linear bf16 store.
//   z=1 (k): RMS + RoPE, per-row chunk-XOR swizzled store (keyed by t&7).
//   z=2 (v): blend with vi, then TRANSPOSED store vT[h][d][t] via LDS
//            (2-pass over the block's 2 heads), chunk-XOR keyed by d&7.
// ---------------------------------------------------------------------------
template<int MODE>
__global__ __launch_bounds__(256) void gemm_bf16_nt(
    const ushort_t* __restrict__ A,
    const ushort_t* __restrict__ B0, const ushort_t* __restrict__ B1,
    const ushort_t* __restrict__ B2,
    void* __restrict__ C0, void* __restrict__ C1, void* __restrict__ C2,
    const float* __restrict__ vi, const float* __restrict__ lamb,
    int M, int N, int K) {
    __shared__ ushort_t smem[16384];          // As | Bs ; reused as V^T buffer
    ushort_t* As = smem;
    ushort_t* Bs = smem + 8192;

    const int z = blockIdx.z;
    const ushort_t* B = (z == 0) ? B0 : (z == 1) ? B1 : B2;
    void* Cv          = (z == 0) ? C0 : (z == 1) ? C1 : C2;

    const int tid = threadIdx.x;
    const int w = tid >> 6;
    const int l = tid & 63;
    const int wr = w >> 1, wc = w & 1;
    const int l16 = l & 15, g4 = l >> 4;
    const int row0 = blockIdx.y * 128;
    const int col0 = blockIdx.x * 128;

    const int srow = tid >> 3;
    const int scol = (tid & 7) * 8;
    const ushort_t* ga = A + (size_t)(row0 + srow) * K + scol;
    const ushort_t* gb = B + (size_t)(col0 + srow) * K + scol;
    ushort_t* lA = &As[w * 512];
    ushort_t* lB = &Bs[w * 512];

    f32x4 acc[4][4];
#pragma unroll
    for (int m = 0; m < 4; ++m)
#pragma unroll
        for (int n = 0; n < 4; ++n)
            acc[m][n] = (f32x4){0.0f, 0.0f, 0.0f, 0.0f};

    for (int k0 = 0; k0 < K; k0 += 64) {
        __syncthreads();
#pragma unroll
        for (int i = 0; i < 4; ++i) {
            gl_lds16(ga + (size_t)i * 32 * K + k0, lA + i * 2048);
            gl_lds16(gb + (size_t)i * 32 * K + k0, lB + i * 2048);
        }
        __syncthreads();
#pragma unroll
        for (int kk = 0; kk < 2; ++kk) {
            short8 af[4], bfr[4];
#pragma unroll
            for (int m = 0; m < 4; ++m)
                af[m] = *(const short8*)&As[(wr * 64 + m * 16 + l16) * 64 + kk * 32 + g4 * 8];
#pragma unroll
            for (int n = 0; n < 4; ++n)
                bfr[n] = *(const short8*)&Bs[(wc * 64 + n * 16 + l16) * 64 + kk * 32 + g4 * 8];
#pragma unroll
            for (int m = 0; m < 4; ++m)
#pragma unroll
                for (int n = 0; n < 4; ++n)
                    acc[m][n] = __builtin_amdgcn_mfma_f32_16x16x32_bf16(af[m], bfr[n], acc[m][n], 0, 0, 0);
        }
    }

    if (MODE == 0) {
#pragma unroll
        for (int m = 0; m < 4; ++m) {
            const int grow = row0 + wr * 64 + m * 16 + g4 * 4;
#pragma unroll
            for (int n = 0; n < 4; ++n) {
                const int gcol = col0 + wc * 64 + n * 16 + l16;
#pragma unroll
                for (int r = 0; r < 4; ++r)
                    ((float*)Cv)[(size_t)(grow + r) * N + gcol] = acc[m][n][r];
            }
        }
    } else {
        const int hh = 2 * blockIdx.x + wc;   // this wave's head
        if (z == 2) {
            // V: blend then transposed store vT[h][d][t] via LDS (2 passes)
            const float lam = lamb[0];
            ushort_t* TB = smem;              // [64][136] u16 = 17408 B
            for (int pass = 0; pass < 2; ++pass) {
                __syncthreads();              // smem free / prev pass stored
                if (wc == pass) {
#pragma unroll
                    for (int m = 0; m < 4; ++m)
#pragma unroll
                        for (int r = 0; r < 4; ++r) {
                            const int trow = wr * 64 + m * 16 + g4 * 4 + r;  // 0..127
                            const int grow = row0 + trow;
#pragma unroll
                            for (int n = 0; n < 4; ++n) {
                                const int d = n * 16 + l16;
                                const float vv = (1.0f - lam) * acc[m][n][r]
                                               + lam * vi[(size_t)grow * D_MODEL + hh * HD + d];
                                TB[d * 136 + trow] = f2bf(vv);
                            }
                        }
                }
                __syncthreads();
                // store head (2*bx+pass): 64 d-rows x 128 t, swizzled 16B chunks
                const int hs = 2 * blockIdx.x + pass;
                const int drow = tid >> 2;        // 0..63
                const int q4 = tid & 3;           // 32-t span
#pragma unroll
                for (int cc = 0; cc < 4; ++cc) {
                    const int cg = q4 * 4 + cc;   // chunk 0..15 (8 t each)
                    const int tile = cg >> 3;
                    const int cw = (cg & 7) ^ (drow & 7);
                    const ushort8 val = *(const ushort8*)&TB[drow * 136 + cg * 8];
                    *(ushort8*)&((ushort_t*)Cv)[(size_t)(hs * 64 + drow) * 2048
                                                + row0 + tile * 64 + cw * 8] = val;
                }
            }
        } else {
#pragma unroll
            for (int m = 0; m < 4; ++m)
#pragma unroll
                for (int r = 0; r < 4; ++r) {
                    const int row = row0 + wr * 64 + m * 16 + g4 * 4 + r;
                    float s = acc[m][0][r] * acc[m][0][r] + acc[m][1][r] * acc[m][1][r]
                            + acc[m][2][r] * acc[m][2][r] + acc[m][3][r] * acc[m][3][r];
                    s += __shfl_xor(s, 1, 64);
                    s += __shfl_xor(s, 2, 64);
                    s += __shfl_xor(s, 4, 64);
                    s += __shfl_xor(s, 8, 64);
                    const float rq = rsqrtf(s * (1.0f / 64.0f) + RMS_EPS);
                    float a[4];
#pragma unroll
                    for (int n = 0; n < 4; ++n) a[n] = acc[m][n][r] * rq;
#pragma unroll
                    for (int n = 0; n < 2; ++n) {
                        const int i = n * 16 + l16;
                        const float inv = exp2f(-0.4152410118609203f * (float)i);
                        float sn, c;
                        sincosf((float)row * inv, &sn, &c);
                        const float a0 = a[n], a2 = a[n + 2];
                        a[n]     = a0 * c + a2 * sn;
                        a[n + 2] = -a0 * sn + a2 * c;
                    }
#pragma unroll
                    for (int n = 0; n < 4; ++n) {
                        const int d = n * 16 + l16;
                        int col;
                        if (z == 1)
                            col = hh * HD + ((((d >> 3) ^ (row & 7)) << 3) | (d & 7));
                        else
                            col = hh * HD + d;
                        ((ushort_t*)Cv)[(size_t)row * D_MODEL + col] = f2bf(a[n]);
                    }
                }
        }
    }
}

// ---------------------------------------------------------------------------
// Flash attention v8: K AND V both via global_load_lds into dbuf LDS
// (V source is the pre-transposed vT[h][d][t] -- no Vt transpose, no V regs,
// ONE barrier/iter). Split-K, swapped QK^T, cvt_pk P-stores as r10.
// ---------------------------------------------------------------------------
__global__ __launch_bounds__(256, 3) void attn_mfma(const ushort_t* __restrict__ qb,
                                                    const ushort_t* __restrict__ kb,
                                                    const ushort_t* __restrict__ vT,
                                                    const float* __restrict__ sink,
                                                    ushort_t* __restrict__ yb,
                                                    float* __restrict__ part_acc,
                                                    float* __restrict__ part_ml) {
    const int b = blockIdx.x;
    int h, qt, kt0, kt1, mode;   // mode 0 = full->y, 1/2 = partial half 0/1
    if (b < 512) {
        qt = 31 - (b >> 5);
        const int rem = b & 31;
        h = rem >> 1;
        const int half = rem & 1;
        const int mid = (qt + 1) >> 1;
        kt0 = half ? mid : 0;
        kt1 = half ? (qt + 1) : mid;
        mode = 1 + half;
    } else {
        const int rem = b - 512;
        qt = 15 - (rem >> 4);
        h = rem & 15;
        kt0 = 0; kt1 = qt + 1; mode = 0;
    }

    __shared__ ushort_t Kl[2][64 * 64];     // K tiles (swizzled rows), dbuf
    __shared__ ushort_t Vl[2][64 * 64];     // V^T tiles (swizzled rows), dbuf
    __shared__ ushort_t Pl[4][16][72];      // per-wave P

    const int tid  = threadIdx.x;
    const int w    = tid >> 6;
    const int lane = tid & 63;
    const int l16  = lane & 15;
    const int g4   = lane >> 4;

    const size_t qoff = (size_t)(qt * 64 + w * 16 + l16) * D_MODEL + h * HD;
    const short8 q0 = *(const short8*)&qb[qoff + 8 * g4];
    const short8 q1 = *(const short8*)&qb[qoff + 32 + 8 * g4];

    const int srow8  = w * 16 + (lane >> 3);   // staging row (+ i*8)
    const int scol_l = (lane & 7) * 8;

    // prologue: DMA K tile kt0 (rows=keys) and V^T tile kt0 (rows=d)
#pragma unroll
    for (int i = 0; i < 2; ++i) {
        gl_lds16(kb + ((size_t)(kt0 * 64 + srow8 + i * 8) << 10) + h * HD + scol_l,
                 &Kl[kt0 & 1][w * 1024 + i * 512]);
        gl_lds16(vT + ((size_t)(h * 64 + srow8 + i * 8) << 11) + kt0 * 64 + scol_l,
                 &Vl[kt0 & 1][w * 1024 + i * 512]);
    }

    float m = -INFINITY, lsum = 0.0f;
    f32x4 acc[4];
#pragma unroll
    for (int d = 0; d < 4; ++d) acc[d] = (f32x4){0.0f, 0.0f, 0.0f, 0.0f};

    for (int kt = kt0; kt < kt1; ++kt) {
        const int cur = kt & 1;

        __syncthreads();   // drains DMA[cur]; all prev reads of [cur^1] done

        // earliest legal DMA issue for next tile (into the just-freed buffer)
        if (kt + 1 < kt1) {
            const int nxt = cur ^ 1;
#pragma unroll
            for (int i = 0; i < 2; ++i) {
                gl_lds16(kb + ((size_t)((kt + 1) * 64 + srow8 + i * 8) << 10) + h * HD + scol_l,
                         &Kl[nxt][w * 1024 + i * 512]);
                gl_lds16(vT + ((size_t)(h * 64 + srow8 + i * 8) << 11) + (kt + 1) * 64 + scol_l,
                         &Vl[nxt][w * 1024 + i * 512]);
            }
        }

        // ---- K A-frags from LDS (swizzled), S^T = K Q^T ----
        f32x4 sf[4];
#pragma unroll
        for (int s = 0; s < 4; ++s) {
            const int row = s * 16 + l16;
            const int swz = l16 & 7;
            const short8 ka0 = *(const short8*)&Kl[cur][row * 64 + ((g4 ^ swz) << 3)];
            const short8 ka1 = *(const short8*)&Kl[cur][row * 64 + (((g4 + 4) ^ swz) << 3)];
            f32x4 t = (f32x4){0.0f, 0.0f, 0.0f, 0.0f};
            t = __builtin_amdgcn_mfma_f32_16x16x32_bf16(ka0, q0, t, 0, 0, 0);
            t = __builtin_amdgcn_mfma_f32_16x16x32_bf16(ka1, q1, t, 0, 0, 0);
            sf[s] = t;
        }

        float mt = -INFINITY;
        if (kt == qt) {
            const int ql = w * 16 + l16;
#pragma unroll
            for (int s = 0; s < 4; ++s)
#pragma unroll
                for (int r = 0; r < 4; ++r) {
                    const float sc = sf[s][r] * 0.125f;
                    sf[s][r] = (s * 16 + g4 * 4 + r > ql) ? -INFINITY : sc;
                    mt = fmaxf(mt, sf[s][r]);
                }
        } else {
#pragma unroll
            for (int s = 0; s < 4; ++s)
#pragma unroll
                for (int r = 0; r < 4; ++r) {
                    sf[s][r] *= 0.125f;
                    mt = fmaxf(mt, sf[s][r]);
                }
        }
        mt = fmaxf(mt, __shfl_xor(mt, 16, 64));
        mt = fmaxf(mt, __shfl_xor(mt, 32, 64));

        const float mnew = fmaxf(m, mt);
        const float corr = __expf(m - mnew);
        m = mnew;

        float ps = 0.0f;
#pragma unroll
        for (int s = 0; s < 4; ++s) {
            const float e0 = __expf(sf[s][0] - m);
            const float e1 = __expf(sf[s][1] - m);
            const float e2 = __expf(sf[s][2] - m);
            const float e3 = __expf(sf[s][3] - m);
            ps += (e0 + e1) + (e2 + e3);
            uint2 pk;
            pk.x = cvt_pk_bf16(e0, e1);
            pk.y = cvt_pk_bf16(e2, e3);
            *(uint2*)&Pl[w][l16][s * 16 + g4 * 4] = pk;
        }
        ps += __shfl_xor(ps, 16, 64);
        ps += __shfl_xor(ps, 32, 64);
        lsum = lsum * corr + ps;

        float corrq[4];
#pragma unroll
        for (int r = 0; r < 4; ++r) corrq[r] = __shfl(corr, g4 * 4 + r, 64);
#pragma unroll
        for (int d = 0; d < 4; ++d)
#pragma unroll
            for (int r = 0; r < 4; ++r) acc[d][r] *= corrq[r];

        // ---- PV: B-frags straight from Vl[cur] (V^T rows, swizzled) ----
        const short8 pa0 = *(const short8*)&Pl[w][l16][8 * g4];
        const short8 pa1 = *(const short8*)&Pl[w][l16][32 + 8 * g4];
#pragma unroll
        for (int d = 0; d < 4; ++d) {
            const int row = d * 16 + l16;
            const int swz = l16 & 7;
            const short8 v0 = *(const short8*)&Vl[cur][row * 64 + ((g4 ^ swz) << 3)];
            const short8 v1 = *(const short8*)&Vl[cur][row * 64 + (((g4 + 4) ^ swz) << 3)];
            acc[d] = __builtin_amdgcn_mfma_f32_16x16x32_bf16(pa0, v0, acc[d], 0, 0, 0);
            acc[d] = __builtin_amdgcn_mfma_f32_16x16x32_bf16(pa1, v1, acc[d], 0, 0, 0);
        }
    }

    if (mode == 0) {
        const float lse = m + __logf(lsum);
        const float scale = 1.0f / (1.0f + __expf(-(lse - sink[h])));
        const float fv = scale / lsum;
        float fq[4];
#pragma unroll
        for (int r = 0; r < 4; ++r) fq[r] = __shfl(fv, g4 * 4 + r, 64);
#pragma unroll
        for (int r = 0; r < 4; ++r) {
            const size_t yoff = (size_t)(qt * 64 + w * 16 + g4 * 4 + r) * D_MODEL + h * HD + l16;
#pragma unroll
            for (int d = 0; d < 4; ++d)
                yb[yoff + d * 16] = f2bf(acc[d][r] * fq[r]);
        }
    } else {
        const int pi = ((qt - 16) * 16 + h) * 2 + (mode - 1);
        if (g4 == 0) {
            float* ml = part_ml + (size_t)pi * 128;
            ml[w * 16 + l16]      = m;
            ml[64 + w * 16 + l16] = lsum;
        }
        float* pa = part_acc + (size_t)pi * 4096;
#pragma unroll
        for (int r = 0; r < 4; ++r) {
            const int row = w * 16 + g4 * 4 + r;
#pragma unroll
            for (int d = 0; d < 4; ++d)
                pa[row * 64 + d * 16 + l16] = acc[d][r];
        }
    }
}

// ---------------------------------------------------------------------------
// Merge the two key-half partials for qt>=16 and apply sink scaling.
// ---------------------------------------------------------------------------
__global__ __launch_bounds__(256) void attn_combine(const float* __restrict__ part_acc,
                                                    const float* __restrict__ part_ml,
                                                    const float* __restrict__ sink,
                                                    ushort_t* __restrict__ yb) {
    const int si = blockIdx.x;          // (qt-16)*16 + h
    const int h  = si & 15;
    const int qt = 16 + (si >> 4);
    const int t  = threadIdx.x;
    const int row = t >> 2;
    const int c0  = (t & 3) * 16;

    const float* a0 = part_acc + ((size_t)si * 2) * 4096 + row * 64 + c0;
    const float* a1 = a0 + 4096;
    const float* ml = part_ml + (size_t)si * 2 * 128;
    const float m0 = ml[row],       l0 = ml[64 + row];
    const float m1 = ml[128 + row], l1 = ml[192 + row];
    const float M  = fmaxf(m0, m1);
    const float e0 = __expf(m0 - M), e1 = __expf(m1 - M);
    const float l  = l0 * e0 + l1 * e1;
    const float lse = M + __logf(l);
    const float scale = 1.0f / (1.0f + __expf(-(lse - sink[h])));
    const float f = scale / l;

    ushort8 o[2];
#pragma unroll
    for (int j = 0; j < 16; ++j) {
        const float v = (a0[j] * e0 + a1[j] * e1) * f;
        o[j >> 3][j & 7] = f2bf(v);
    }
    ushort_t* yp = yb + (size_t)(qt * 64 + row) * D_MODEL + h * HD + c0;
    *(ushort8*)yp       = o[0];
    *(ushort8*)(yp + 8) = o[1];
}

// ---------------------------------------------------------------------------
extern "C" void kernel_launch(void* const* d_in, const int* in_sizes, int n_in,
                              void* d_out, int out_size, void* d_ws, size_t ws_size,
                              hipStream_t stream) {
    const float* x    = (const float*)d_in[0];
    const float* vi   = (const float*)d_in[1];
    const float* Wq   = (const float*)d_in[2];
    const float* Wk   = (const float*)d_in[3];
    const float* Wv   = (const float*)d_in[4];
    const float* Wo   = (const float*)d_in[5];
    const float* lamb = (const float*)d_in[6];
    const float* sink = (const float*)d_in[7];
    float* out = (float*)d_out;

    const size_t TD = (size_t)T_SEQ * D_MODEL;    // 2M elts
    const size_t WD = (size_t)D_MODEL * D_MODEL;  // 1M elts
    ushort_t* qbuf = (ushort_t*)d_ws;             // [ 0, 4)MB
    ushort_t* kbuf = qbuf + TD;                   // [ 4, 8)MB
    ushort_t* vbuf = kbuf + TD;                   // [ 8,12)MB  (= vT[h][d][t])
    ushort_t* yb   = vbuf + TD;                   // [12,16)MB
    ushort_t* wob  = yb + TD;                     // [16,18)MB
    ushort_t* xb   = wob + WD;                    // [18,22)MB
    ushort_t* wqb  = xb + TD;                     // [22,24)MB
    ushort_t* wkb  = wqb + WD;                    // [24,26)MB
    ushort_t* wvb  = wkb + WD;                    // [26,28)MB
    // attn partials overlay the staging buffers (dead after the QKV GEMM):
    float* part_acc = (float*)xb;                 // 8 MB  [18,26)MB
    float* part_ml  = (float*)wvb;                // 256 KB in [26,28)MB

    cast_to_bf16<<<dim3(512, 6), 256, 0, stream>>>(x, Wq, Wk, Wv, Wo,
                                                   xb, wqb, wkb, wvb, wob);

    // fused QKV projection + v-blend + RMSNorm + RoPE + K-swizzle + V-transpose
    gemm_bf16_nt<1><<<dim3(D_MODEL / 128, T_SEQ / 128, 3), 256, 0, stream>>>(
        xb, wqb, wkb, wvb, qbuf, kbuf, vbuf, vi, lamb, T_SEQ, D_MODEL, D_MODEL);

    attn_mfma<<<dim3(768), 256, 0, stream>>>(qbuf, kbuf, vbuf, sink, yb,
                                             part_acc, part_ml);
    attn_combine<<<dim3(256), 256, 0, stream>>>(part_acc, part_ml, sink, yb);

    gemm_bf16_nt<0><<<dim3(D_MODEL / 128, T_SEQ / 128, 1), 256, 0, stream>>>(
        yb, wob, wob, wob, out, out, out, nullptr, nullptr, T_SEQ, D_MODEL, D_MODEL);
}

// Round 17
// 95.698 us; speedup vs baseline: 1.1983x; 1.0198x over previous
//
#include <hip/hip_runtime.h>
#include <math.h>

#define T_SEQ 2048
#define D_MODEL 1024
#define NH 16
#define HD 64
#define RMS_EPS 1.1920928955078125e-07f

typedef unsigned short ushort_t;
typedef __attribute__((ext_vector_type(8))) short short8;
typedef __attribute__((ext_vector_type(8))) unsigned short ushort8;
typedef __attribute__((ext_vector_type(4))) float f32x4;

static __device__ __forceinline__ unsigned short f2bf(float f) {
    union { float f; unsigned u; } v; v.f = f;
    unsigned r = v.u + 0x7fff + ((v.u >> 16) & 1);   // RNE
    return (unsigned short)(r >> 16);
}
static __device__ __forceinline__ unsigned cvt_pk_bf16(float lo, float hi) {
    unsigned r;
    asm("v_cvt_pk_bf16_f32 %0, %1, %2" : "=v"(r) : "v"(lo), "v"(hi));
    return r;
}
static __device__ __forceinline__ void gl_lds16(const ushort_t* g, ushort_t* l) {
    __builtin_amdgcn_global_load_lds(
        (const __attribute__((address_space(1))) unsigned int*)g,
        (__attribute__((address_space(3))) unsigned int*)l, 16, 0, 0);
}

// ---------------------------------------------------------------------------
// Cast f32 -> bf16 (segs 0-5) + RoPE cos/sin table fill (seg 6).
// tab[t*32+i] = (cos, sin)(t * 10000^(-i/32)) -- removes per-element trig
// from the QKV GEMM epilogue (32 sincosf+32 exp2f per thread -> 32 loads).
// ---------------------------------------------------------------------------
__global__ __launch_bounds__(256) void cast_to_bf16(
    const float* __restrict__ x, const float* __restrict__ wq,
    const float* __restrict__ wk, const float* __restrict__ wv,
    const float* __restrict__ wo,
    ushort_t* __restrict__ xb, ushort_t* __restrict__ wqb,
    ushort_t* __restrict__ wkb, ushort_t* __restrict__ wvb,
    ushort_t* __restrict__ wob, float2* __restrict__ rtab) {
    const int seg = blockIdx.y;
    if (seg == 6) {
        if (blockIdx.x < 256) {
            const int t = blockIdx.x * 8 + (threadIdx.x >> 5);
            const int i = threadIdx.x & 31;
            const float inv = exp2f(-0.4152410118609203f * (float)i);
            float sn, c;
            sincosf((float)t * inv, &sn, &c);
            rtab[t * 32 + i] = make_float2(c, sn);
        }
        return;
    }
    const float* src; ushort_t* dst; size_t base = 0;
    if (seg == 0)      { src = x;  dst = xb; }
    else if (seg == 1) { src = x;  dst = xb; base = 1u << 20; }
    else if (seg == 2) { src = wq; dst = wqb; }
    else if (seg == 3) { src = wk; dst = wkb; }
    else if (seg == 4) { src = wv; dst = wvb; }
    else               { src = wo; dst = wob; }
    const size_t i = base + ((size_t)blockIdx.x * 256 + threadIdx.x) * 8;
    float4 a = *(const float4*)&src[i];
    float4 b = *(const float4*)&src[i + 4];
    ushort8 o;
    o[0] = f2bf(a.x); o[1] = f2bf(a.y); o[2] = f2bf(a.z); o[3] = f2bf(a.w);
    o[4] = f2bf(b.x); o[5] = f2bf(b.y); o[6] = f2bf(b.z); o[7] = f2bf(b.w);
    *(ushort8*)&dst[i] = o;
}

// ---------------------------------------------------------------------------
// bf16 MFMA GEMM, r10 config. MODE 0: f32 store (Wo). MODE 1: fused QKV:
//   z=0 (q): RMS + RoPE(table), linear bf16 store.
//   z=1 (k): RMS + RoPE(table), per-row chunk-XOR swizzled store (t&7).
//   z=2 (v): blend with vi, TRANSPOSED store vT[h][d][t] via LDS (d&7 swz).
// ---------------------------------------------------------------------------
template<int MODE>
__global__ __launch_bounds__(256) void gemm_bf16_nt(
    const ushort_t* __restrict__ A,
    const ushort_t* __restrict__ B0, const ushort_t* __restrict__ B1,
    const ushort_t* __restrict__ B2,
    void* __restrict__ C0, void* __restrict__ C1, void* __restrict__ C2,
    const float* __restrict__ vi, const float* __restrict__ lamb,
    const float2* __restrict__ rtab,
    int M, int N, int K) {
    __shared__ ushort_t smem[16384];          // As | Bs ; reused as V^T buffer
    ushort_t* As = smem;
    ushort_t* Bs = smem + 8192;

    const int z = blockIdx.z;
    const ushort_t* B = (z == 0) ? B0 : (z == 1) ? B1 : B2;
    void* Cv          = (z == 0) ? C0 : (z == 1) ? C1 : C2;

    const int tid = threadIdx.x;
    const int w = tid >> 6;
    const int l = tid & 63;
    const int wr = w >> 1, wc = w & 1;
    const int l16 = l & 15, g4 = l >> 4;
    const int row0 = blockIdx.y * 128;
    const int col0 = blockIdx.x * 128;

    const int srow = tid >> 3;
    const int scol = (tid & 7) * 8;
    const ushort_t* ga = A + (size_t)(row0 + srow) * K + scol;
    const ushort_t* gb = B + (size_t)(col0 + srow) * K + scol;
    ushort_t* lA = &As[w * 512];
    ushort_t* lB = &Bs[w * 512];

    f32x4 acc[4][4];
#pragma unroll
    for (int m = 0; m < 4; ++m)
#pragma unroll
        for (int n = 0; n < 4; ++n)
            acc[m][n] = (f32x4){0.0f, 0.0f, 0.0f, 0.0f};

    for (int k0 = 0; k0 < K; k0 += 64) {
        __syncthreads();
#pragma unroll
        for (int i = 0; i < 4; ++i) {
            gl_lds16(ga + (size_t)i * 32 * K + k0, lA + i * 2048);
            gl_lds16(gb + (size_t)i * 32 * K + k0, lB + i * 2048);
        }
        __syncthreads();
#pragma unroll
        for (int kk = 0; kk < 2; ++kk) {
            short8 af[4], bfr[4];
#pragma unroll
            for (int m = 0; m < 4; ++m)
                af[m] = *(const short8*)&As[(wr * 64 + m * 16 + l16) * 64 + kk * 32 + g4 * 8];
#pragma unroll
            for (int n = 0; n < 4; ++n)
                bfr[n] = *(const short8*)&Bs[(wc * 64 + n * 16 + l16) * 64 + kk * 32 + g4 * 8];
#pragma unroll
            for (int m = 0; m < 4; ++m)
#pragma unroll
                for (int n = 0; n < 4; ++n)
                    acc[m][n] = __builtin_amdgcn_mfma_f32_16x16x32_bf16(af[m], bfr[n], acc[m][n], 0, 0, 0);
        }
    }

    if (MODE == 0) {
#pragma unroll
        for (int m = 0; m < 4; ++m) {
            const int grow = row0 + wr * 64 + m * 16 + g4 * 4;
#pragma unroll
            for (int n = 0; n < 4; ++n) {
                const int gcol = col0 + wc * 64 + n * 16 + l16;
#pragma unroll
                for (int r = 0; r < 4; ++r)
                    ((float*)Cv)[(size_t)(grow + r) * N + gcol] = acc[m][n][r];
            }
        }
    } else {
        const int hh = 2 * blockIdx.x + wc;   // this wave's head
        if (z == 2) {
            // V: blend then transposed store vT[h][d][t] via LDS (2 passes)
            const float lam = lamb[0];
            ushort_t* TB = smem;              // [64][136] u16 = 17408 B
            for (int pass = 0; pass < 2; ++pass) {
                __syncthreads();              // smem free / prev pass stored
                if (wc == pass) {
#pragma unroll
                    for (int m = 0; m < 4; ++m)
#pragma unroll
                        for (int r = 0; r < 4; ++r) {
                            const int trow = wr * 64 + m * 16 + g4 * 4 + r;  // 0..127
                            const int grow = row0 + trow;
#pragma unroll
                            for (int n = 0; n < 4; ++n) {
                                const int d = n * 16 + l16;
                                const float vv = (1.0f - lam) * acc[m][n][r]
                                               + lam * vi[(size_t)grow * D_MODEL + hh * HD + d];
                                TB[d * 136 + trow] = f2bf(vv);
                            }
                        }
                }
                __syncthreads();
                // store head (2*bx+pass): 64 d-rows x 128 t, swizzled 16B chunks
                const int hs = 2 * blockIdx.x + pass;
                const int drow = tid >> 2;        // 0..63
                const int q4 = tid & 3;           // 32-t span
#pragma unroll
                for (int cc = 0; cc < 4; ++cc) {
                    const int cg = q4 * 4 + cc;   // chunk 0..15 (8 t each)
                    const int tile = cg >> 3;
                    const int cw = (cg & 7) ^ (drow & 7);
                    const ushort8 val = *(const ushort8*)&TB[drow * 136 + cg * 8];
                    *(ushort8*)&((ushort_t*)Cv)[(size_t)(hs * 64 + drow) * 2048
                                                + row0 + tile * 64 + cw * 8] = val;
                }
            }
        } else {
#pragma unroll
            for (int m = 0; m < 4; ++m)
#pragma unroll
                for (int r = 0; r < 4; ++r) {
                    const int row = row0 + wr * 64 + m * 16 + g4 * 4 + r;
                    float s = acc[m][0][r] * acc[m][0][r] + acc[m][1][r] * acc[m][1][r]
                            + acc[m][2][r] * acc[m][2][r] + acc[m][3][r] * acc[m][3][r];
                    s += __shfl_xor(s, 1, 64);
                    s += __shfl_xor(s, 2, 64);
                    s += __shfl_xor(s, 4, 64);
                    s += __shfl_xor(s, 8, 64);
                    const float rq = rsqrtf(s * (1.0f / 64.0f) + RMS_EPS);
                    float a[4];
#pragma unroll
                    for (int n = 0; n < 4; ++n) a[n] = acc[m][n][r] * rq;
                    // RoPE via precomputed table (pair d, d+32 = frag n, n+2)
                    const float2 cs0 = rtab[row * 32 + l16];
                    const float2 cs1 = rtab[row * 32 + 16 + l16];
#pragma unroll
                    for (int n = 0; n < 2; ++n) {
                        const float c  = n ? cs1.x : cs0.x;
                        const float sn = n ? cs1.y : cs0.y;
                        const float a0 = a[n], a2 = a[n + 2];
                        a[n]     = a0 * c + a2 * sn;
                        a[n + 2] = -a0 * sn + a2 * c;
                    }
#pragma unroll
                    for (int n = 0; n < 4; ++n) {
                        const int d = n * 16 + l16;
                        int col;
                        if (z == 1)
                            col = hh * HD + ((((d >> 3) ^ (row & 7)) << 3) | (d & 7));
                        else
                            col = hh * HD + d;
                        ((ushort_t*)Cv)[(size_t)row * D_MODEL + col] = f2bf(a[n]);
                    }
                }
        }
    }
}

// ---------------------------------------------------------------------------
// Flash attention v8 (r16 verbatim): K AND V via global_load_lds dbuf LDS
// (V source pre-transposed vT[h][d][t]); one barrier/iter; split-K; swapped
// QK^T; cvt_pk P-stores.
// ---------------------------------------------------------------------------
__global__ __launch_bounds__(256, 3) void attn_mfma(const ushort_t* __restrict__ qb,
                                                    const ushort_t* __restrict__ kb,
                                                    const ushort_t* __restrict__ vT,
                                                    const float* __restrict__ sink,
                                                    ushort_t* __restrict__ yb,
                                                    float* __restrict__ part_acc,
                                                    float* __restrict__ part_ml) {
    const int b = blockIdx.x;
    int h, qt, kt0, kt1, mode;   // mode 0 = full->y, 1/2 = partial half 0/1
    if (b < 512) {
        qt = 31 - (b >> 5);
        const int rem = b & 31;
        h = rem >> 1;
        const int half = rem & 1;
        const int mid = (qt + 1) >> 1;
        kt0 = half ? mid : 0;
        kt1 = half ? (qt + 1) : mid;
        mode = 1 + half;
    } else {
        const int rem = b - 512;
        qt = 15 - (rem >> 4);
        h = rem & 15;
        kt0 = 0; kt1 = qt + 1; mode = 0;
    }

    __shared__ ushort_t Kl[2][64 * 64];     // K tiles (swizzled rows), dbuf
    __shared__ ushort_t Vl[2][64 * 64];     // V^T tiles (swizzled rows), dbuf
    __shared__ ushort_t Pl[4][16][72];      // per-wave P

    const int tid  = threadIdx.x;
    const int w    = tid >> 6;
    const int lane = tid & 63;
    const int l16  = lane & 15;
    const int g4   = lane >> 4;

    const size_t qoff = (size_t)(qt * 64 + w * 16 + l16) * D_MODEL + h * HD;
    const short8 q0 = *(const short8*)&qb[qoff + 8 * g4];
    const short8 q1 = *(const short8*)&qb[qoff + 32 + 8 * g4];

    const int srow8  = w * 16 + (lane >> 3);   // staging row (+ i*8)
    const int scol_l = (lane & 7) * 8;

    // prologue: DMA K tile kt0 (rows=keys) and V^T tile kt0 (rows=d)
#pragma unroll
    for (int i = 0; i < 2; ++i) {
        gl_lds16(kb + ((size_t)(kt0 * 64 + srow8 + i * 8) << 10) + h * HD + scol_l,
                 &Kl[kt0 & 1][w * 1024 + i * 512]);
        gl_lds16(vT + ((size_t)(h * 64 + srow8 + i * 8) << 11) + kt0 * 64 + scol_l,
                 &Vl[kt0 & 1][w * 1024 + i * 512]);
    }

    float m = -INFINITY, lsum = 0.0f;
    f32x4 acc[4];
#pragma unroll
    for (int d = 0; d < 4; ++d) acc[d] = (f32x4){0.0f, 0.0f, 0.0f, 0.0f};

    for (int kt = kt0; kt < kt1; ++kt) {
        const int cur = kt & 1;

        __syncthreads();   // drains DMA[cur]; all prev reads of [cur^1] done

        // earliest legal DMA issue for next tile (into the just-freed buffer)
        if (kt + 1 < kt1) {
            const int nxt = cur ^ 1;
#pragma unroll
            for (int i = 0; i < 2; ++i) {
                gl_lds16(kb + ((size_t)((kt + 1) * 64 + srow8 + i * 8) << 10) + h * HD + scol_l,
                         &Kl[nxt][w * 1024 + i * 512]);
                gl_lds16(vT + ((size_t)(h * 64 + srow8 + i * 8) << 11) + (kt + 1) * 64 + scol_l,
                         &Vl[nxt][w * 1024 + i * 512]);
            }
        }

        // ---- K A-frags from LDS (swizzled), S^T = K Q^T ----
        f32x4 sf[4];
#pragma unroll
        for (int s = 0; s < 4; ++s) {
            const int row = s * 16 + l16;
            const int swz = l16 & 7;
            const short8 ka0 = *(const short8*)&Kl[cur][row * 64 + ((g4 ^ swz) << 3)];
            const short8 ka1 = *(const short8*)&Kl[cur][row * 64 + (((g4 + 4) ^ swz) << 3)];
            f32x4 t = (f32x4){0.0f, 0.0f, 0.0f, 0.0f};
            t = __builtin_amdgcn_mfma_f32_16x16x32_bf16(ka0, q0, t, 0, 0, 0);
            t = __builtin_amdgcn_mfma_f32_16x16x32_bf16(ka1, q1, t, 0, 0, 0);
            sf[s] = t;
        }

        float mt = -INFINITY;
        if (kt == qt) {
            const int ql = w * 16 + l16;
#pragma unroll
            for (int s = 0; s < 4; ++s)
#pragma unroll
                for (int r = 0; r < 4; ++r) {
                    const float sc = sf[s][r] * 0.125f;
                    sf[s][r] = (s * 16 + g4 * 4 + r > ql) ? -INFINITY : sc;
                    mt = fmaxf(mt, sf[s][r]);
                }
        } else {
#pragma unroll
            for (int s = 0; s < 4; ++s)
#pragma unroll
                for (int r = 0; r < 4; ++r) {
                    sf[s][r] *= 0.125f;
                    mt = fmaxf(mt, sf[s][r]);
                }
        }
        mt = fmaxf(mt, __shfl_xor(mt, 16, 64));
        mt = fmaxf(mt, __shfl_xor(mt, 32, 64));

        const float mnew = fmaxf(m, mt);
        const float corr = __expf(m - mnew);
        m = mnew;

        float ps = 0.0f;
#pragma unroll
        for (int s = 0; s < 4; ++s) {
            const float e0 = __expf(sf[s][0] - m);
            const float e1 = __expf(sf[s][1] - m);
            const float e2 = __expf(sf[s][2] - m);
            const float e3 = __expf(sf[s][3] - m);
            ps += (e0 + e1) + (e2 + e3);
            uint2 pk;
            pk.x = cvt_pk_bf16(e0, e1);
            pk.y = cvt_pk_bf16(e2, e3);
            *(uint2*)&Pl[w][l16][s * 16 + g4 * 4] = pk;
        }
        ps += __shfl_xor(ps, 16, 64);
        ps += __shfl_xor(ps, 32, 64);
        lsum = lsum * corr + ps;

        float corrq[4];
#pragma unroll
        for (int r = 0; r < 4; ++r) corrq[r] = __shfl(corr, g4 * 4 + r, 64);
#pragma unroll
        for (int d = 0; d < 4; ++d)
#pragma unroll
            for (int r = 0; r < 4; ++r) acc[d][r] *= corrq[r];

        // ---- PV: B-frags straight from Vl[cur] (V^T rows, swizzled) ----
        const short8 pa0 = *(const short8*)&Pl[w][l16][8 * g4];
        const short8 pa1 = *(const short8*)&Pl[w][l16][32 + 8 * g4];
#pragma unroll
        for (int d = 0; d < 4; ++d) {
            const int row = d * 16 + l16;
            const int swz = l16 & 7;
            const short8 v0 = *(const short8*)&Vl[cur][row * 64 + ((g4 ^ swz) << 3)];
            const short8 v1 = *(const short8*)&Vl[cur][row * 64 + (((g4 + 4) ^ swz) << 3)];
            acc[d] = __builtin_amdgcn_mfma_f32_16x16x32_bf16(pa0, v0, acc[d], 0, 0, 0);
            acc[d] = __builtin_amdgcn_mfma_f32_16x16x32_bf16(pa1, v1, acc[d], 0, 0, 0);
        }
    }

    if (mode == 0) {
        const float lse = m + __logf(lsum);
        const float scale = 1.0f / (1.0f + __expf(-(lse - sink[h])));
        const float fv = scale / lsum;
        float fq[4];
#pragma unroll
        for (int r = 0; r < 4; ++r) fq[r] = __shfl(fv, g4 * 4 + r, 64);
#pragma unroll
        for (int r = 0; r < 4; ++r) {
            const size_t yoff = (size_t)(qt * 64 + w * 16 + g4 * 4 + r) * D_MODEL + h * HD + l16;
#pragma unroll
            for (int d = 0; d < 4; ++d)
                yb[yoff + d * 16] = f2bf(acc[d][r] * fq[r]);
        }
    } else {
        const int pi = ((qt - 16) * 16 + h) * 2 + (mode - 1);
        if (g4 == 0) {
            float* ml = part_ml + (size_t)pi * 128;
            ml[w * 16 + l16]      = m;
            ml[64 + w * 16 + l16] = lsum;
        }
        float* pa = part_acc + (size_t)pi * 4096;
#pragma unroll
        for (int r = 0; r < 4; ++r) {
            const int row = w * 16 + g4 * 4 + r;
#pragma unroll
            for (int d = 0; d < 4; ++d)
                pa[row * 64 + d * 16 + l16] = acc[d][r];
        }
    }
}

// ---------------------------------------------------------------------------
// Merge the two key-half partials for qt>=16 and apply sink scaling.
// ---------------------------------------------------------------------------
__global__ __launch_bounds__(256) void attn_combine(const float* __restrict__ part_acc,
                                                    const float* __restrict__ part_ml,
                                                    const float* __restrict__ sink,
                                                    ushort_t* __restrict__ yb) {
    const int si = blockIdx.x;          // (qt-16)*16 + h
    const int h  = si & 15;
    const int qt = 16 + (si >> 4);
    const int t  = threadIdx.x;
    const int row = t >> 2;
    const int c0  = (t & 3) * 16;

    const float* a0 = part_acc + ((size_t)si * 2) * 4096 + row * 64 + c0;
    const float* a1 = a0 + 4096;
    const float* ml = part_ml + (size_t)si * 2 * 128;
    const float m0 = ml[row],       l0 = ml[64 + row];
    const float m1 = ml[128 + row], l1 = ml[192 + row];
    const float M  = fmaxf(m0, m1);
    const float e0 = __expf(m0 - M), e1 = __expf(m1 - M);
    const float l  = l0 * e0 + l1 * e1;
    const float lse = M + __logf(l);
    const float scale = 1.0f / (1.0f + __expf(-(lse - sink[h])));
    const float f = scale / l;

    ushort8 o[2];
#pragma unroll
    for (int j = 0; j < 16; ++j) {
        const float v = (a0[j] * e0 + a1[j] * e1) * f;
        o[j >> 3][j & 7] = f2bf(v);
    }
    ushort_t* yp = yb + (size_t)(qt * 64 + row) * D_MODEL + h * HD + c0;
    *(ushort8*)yp       = o[0];
    *(ushort8*)(yp + 8) = o[1];
}

// ---------------------------------------------------------------------------
extern "C" void kernel_launch(void* const* d_in, const int* in_sizes, int n_in,
                              void* d_out, int out_size, void* d_ws, size_t ws_size,
                              hipStream_t stream) {
    const float* x    = (const float*)d_in[0];
    const float* vi   = (const float*)d_in[1];
    const float* Wq   = (const float*)d_in[2];
    const float* Wk   = (const float*)d_in[3];
    const float* Wv   = (const float*)d_in[4];
    const float* Wo   = (const float*)d_in[5];
    const float* lamb = (const float*)d_in[6];
    const float* sink = (const float*)d_in[7];
    float* out = (float*)d_out;

    const size_t TD = (size_t)T_SEQ * D_MODEL;    // 2M elts
    const size_t WD = (size_t)D_MODEL * D_MODEL;  // 1M elts
    ushort_t* qbuf = (ushort_t*)d_ws;             // [ 0, 4)MB
    ushort_t* kbuf = qbuf + TD;                   // [ 4, 8)MB
    ushort_t* vbuf = kbuf + TD;                   // [ 8,12)MB  (= vT[h][d][t])
    ushort_t* yb   = vbuf + TD;                   // [12,16)MB
    ushort_t* wob  = yb + TD;                     // [16,18)MB
    ushort_t* xb   = wob + WD;                    // [18,22)MB
    ushort_t* wqb  = xb + TD;                     // [22,24)MB
    ushort_t* wkb  = wqb + WD;                    // [24,26)MB
    ushort_t* wvb  = wkb + WD;                    // [26,28)MB
    float2*   rtab = (float2*)(wvb + WD);         // [28,28.5)MB RoPE table
    // attn partials overlay the staging buffers (dead after the QKV GEMM):
    float* part_acc = (float*)xb;                 // 8 MB  [18,26)MB
    float* part_ml  = (float*)wvb;                // 256 KB in [26,28)MB

    cast_to_bf16<<<dim3(512, 7), 256, 0, stream>>>(x, Wq, Wk, Wv, Wo,
                                                   xb, wqb, wkb, wvb, wob, rtab);

    // fused QKV projection + v-blend + RMSNorm + RoPE + K-swizzle + V-transpose
    gemm_bf16_nt<1><<<dim3(D_MODEL / 128, T_SEQ / 128, 3), 256, 0, stream>>>(
        xb, wqb, wkb, wvb, qbuf, kbuf, vbuf, vi, lamb, rtab, T_SEQ, D_MODEL, D_MODEL);

    attn_mfma<<<dim3(768), 256, 0, stream>>>(qbuf, kbuf, vbuf, sink, yb,
                                             part_acc, part_ml);
    attn_combine<<<dim3(256), 256, 0, stream>>>(part_acc, part_ml, sink, yb);

    gemm_bf16_nt<0><<<dim3(D_MODEL / 128, T_SEQ / 128, 1), 256, 0, stream>>>(
        yb, wob, wob, wob, out, out, out, nullptr, nullptr, nullptr,
        T_SEQ, D_MODEL, D_MODEL);
}

// Round 18
// 84.568 us; speedup vs baseline: 1.3560x; 1.1316x over previous
//
#include <hip/hip_runtime.h>
#include <math.h>

#define T_SEQ 2048
#define D_MODEL 1024
#define NH 16
#define HD 64
#define RMS_EPS 1.1920928955078125e-07f

typedef unsigned short ushort_t;
typedef __attribute__((ext_vector_type(8))) short short8;
typedef __attribute__((ext_vector_type(8))) unsigned short ushort8;
typedef __attribute__((ext_vector_type(4))) float f32x4;

static __device__ __forceinline__ unsigned short f2bf(float f) {
    union { float f; unsigned u; } v; v.f = f;
    unsigned r = v.u + 0x7fff + ((v.u >> 16) & 1);   // RNE
    return (unsigned short)(r >> 16);
}
static __device__ __forceinline__ unsigned cvt_pk_bf16(float lo, float hi) {
    unsigned r;
    asm("v_cvt_pk_bf16_f32 %0, %1, %2" : "=v"(r) : "v"(lo), "v"(hi));
    return r;
}
static __device__ __forceinline__ void gl_lds16(const ushort_t* g, ushort_t* l) {
    __builtin_amdgcn_global_load_lds(
        (const __attribute__((address_space(1))) unsigned int*)g,
        (__attribute__((address_space(3))) unsigned int*)l, 16, 0, 0);
}

// ---------------------------------------------------------------------------
// Cast f32 -> bf16 (segs 0-5) + RoPE cos/sin table fill (seg 6).
// ---------------------------------------------------------------------------
__global__ __launch_bounds__(256) void cast_to_bf16(
    const float* __restrict__ x, const float* __restrict__ wq,
    const float* __restrict__ wk, const float* __restrict__ wv,
    const float* __restrict__ wo,
    ushort_t* __restrict__ xb, ushort_t* __restrict__ wqb,
    ushort_t* __restrict__ wkb, ushort_t* __restrict__ wvb,
    ushort_t* __restrict__ wob, float2* __restrict__ rtab) {
    const int seg = blockIdx.y;
    if (seg == 6) {
        if (blockIdx.x < 256) {
            const int t = blockIdx.x * 8 + (threadIdx.x >> 5);
            const int i = threadIdx.x & 31;
            const float inv = exp2f(-0.4152410118609203f * (float)i);
            float sn, c;
            sincosf((float)t * inv, &sn, &c);
            rtab[t * 32 + i] = make_float2(c, sn);
        }
        return;
    }
    const float* src; ushort_t* dst; size_t base = 0;
    if (seg == 0)      { src = x;  dst = xb; }
    else if (seg == 1) { src = x;  dst = xb; base = 1u << 20; }
    else if (seg == 2) { src = wq; dst = wqb; }
    else if (seg == 3) { src = wk; dst = wkb; }
    else if (seg == 4) { src = wv; dst = wvb; }
    else               { src = wo; dst = wob; }
    const size_t i = base + ((size_t)blockIdx.x * 256 + threadIdx.x) * 8;
    float4 a = *(const float4*)&src[i];
    float4 b = *(const float4*)&src[i + 4];
    ushort8 o;
    o[0] = f2bf(a.x); o[1] = f2bf(a.y); o[2] = f2bf(a.z); o[3] = f2bf(a.w);
    o[4] = f2bf(b.x); o[5] = f2bf(b.y); o[6] = f2bf(b.z); o[7] = f2bf(b.w);
    *(ushort8*)&dst[i] = o;
}

// ---------------------------------------------------------------------------
// Templated bf16 MFMA GEMM (2-barrier, gl_lds staging). 256 threads,
// NWM x NWN = 4 waves. Re-tiled for >=2 blocks/CU (r17 counters: grid 384/
// 128 blocks = 0.5-1.5 blocks/CU left the barrier drain unoverlapped).
// MODE 0: f32 store (Wo), 64x64 tile -> 512 blocks.
// MODE 1: fused QKV epilogue, 64x128 tile -> 768 blocks; wave col-span = 64
//   = one head (hh = blockIdx.x*(BN/64) + wc):
//   z=0 (q): RMS + RoPE(table), linear bf16 store.
//   z=1 (k): RMS + RoPE(table), chunk-XOR swizzled store (keyed t&7).
//   z=2 (v): blend with vi, transposed store vT[h][d][t] via LDS (d&7 swz).
// ---------------------------------------------------------------------------
template<int BM, int BN, int NWM, int NWN, int MODE>
__global__ __launch_bounds__(256) void gemm_bf16_nt(
    const ushort_t* __restrict__ A,
    const ushort_t* __restrict__ B0, const ushort_t* __restrict__ B1,
    const ushort_t* __restrict__ B2,
    void* __restrict__ C0, void* __restrict__ C1, void* __restrict__ C2,
    const float* __restrict__ vi, const float* __restrict__ lamb,
    const float2* __restrict__ rtab,
    int M, int N, int K) {
    constexpr int NT  = 256;
    constexpr int WM  = BM / NWM;
    constexpr int WN  = BN / NWN;
    constexpr int MF  = WM / 16, NF = WN / 16;
    constexpr int RPC = NT / 8;              // rows per 16B staging call
    constexpr int CA  = BM / RPC;
    constexpr int CB  = BN / RPC;

    __shared__ ushort_t smem[(BM + BN) * 64];
    ushort_t* As = smem;
    ushort_t* Bs = smem + BM * 64;

    const int z = blockIdx.z;
    const ushort_t* B = (z == 0) ? B0 : (z == 1) ? B1 : B2;
    void* Cv          = (z == 0) ? C0 : (z == 1) ? C1 : C2;

    const int tid = threadIdx.x;
    const int w = tid >> 6;
    const int l = tid & 63;
    const int wr = w / NWN, wc = w % NWN;
    const int l16 = l & 15, g4 = l >> 4;
    const int row0 = blockIdx.y * BM;
    const int col0 = blockIdx.x * BN;

    const int srow = tid >> 3;
    const int scol = (tid & 7) * 8;
    const ushort_t* ga = A + (size_t)(row0 + srow) * K + scol;
    const ushort_t* gb = B + (size_t)(col0 + srow) * K + scol;
    ushort_t* lA = &As[w * 512];
    ushort_t* lB = &Bs[w * 512];

    f32x4 acc[MF][NF];
#pragma unroll
    for (int m = 0; m < MF; ++m)
#pragma unroll
        for (int n = 0; n < NF; ++n)
            acc[m][n] = (f32x4){0.0f, 0.0f, 0.0f, 0.0f};

    for (int k0 = 0; k0 < K; k0 += 64) {
        __syncthreads();
#pragma unroll
        for (int i = 0; i < CA; ++i)
            gl_lds16(ga + (size_t)i * RPC * K + k0, lA + i * NT * 8);
#pragma unroll
        for (int i = 0; i < CB; ++i)
            gl_lds16(gb + (size_t)i * RPC * K + k0, lB + i * NT * 8);
        __syncthreads();
#pragma unroll
        for (int kk = 0; kk < 2; ++kk) {
            short8 af[MF], bfr[NF];
#pragma unroll
            for (int m = 0; m < MF; ++m)
                af[m] = *(const short8*)&As[(wr * WM + m * 16 + l16) * 64 + kk * 32 + g4 * 8];
#pragma unroll
            for (int n = 0; n < NF; ++n)
                bfr[n] = *(const short8*)&Bs[(wc * WN + n * 16 + l16) * 64 + kk * 32 + g4 * 8];
#pragma unroll
            for (int m = 0; m < MF; ++m)
#pragma unroll
                for (int n = 0; n < NF; ++n)
                    acc[m][n] = __builtin_amdgcn_mfma_f32_16x16x32_bf16(af[m], bfr[n], acc[m][n], 0, 0, 0);
        }
    }

    if (MODE == 0) {
#pragma unroll
        for (int m = 0; m < MF; ++m) {
            const int grow = row0 + wr * WM + m * 16 + g4 * 4;
#pragma unroll
            for (int n = 0; n < NF; ++n) {
                const int gcol = col0 + wc * WN + n * 16 + l16;
#pragma unroll
                for (int r = 0; r < 4; ++r)
                    ((float*)Cv)[(size_t)(grow + r) * N + gcol] = acc[m][n][r];
            }
        }
    } else {
        const int hh = blockIdx.x * (BN / 64) + wc;   // this wave's head
        if (z == 2) {
            // V: blend then transposed store vT[h][d][t] via LDS, per head
            const float lam = lamb[0];
            ushort_t* TB = smem;              // [64 d][72] u16 = 9216 B
            for (int pass = 0; pass < NWN; ++pass) {
                __syncthreads();              // smem free / prev pass stored
                if (wc == pass) {
#pragma unroll
                    for (int m = 0; m < MF; ++m)
#pragma unroll
                        for (int r = 0; r < 4; ++r) {
                            const int trow = wr * WM + m * 16 + g4 * 4 + r;  // 0..BM-1
                            const int grow = row0 + trow;
#pragma unroll
                            for (int n = 0; n < NF; ++n) {
                                const int d = n * 16 + l16;
                                const float vv = (1.0f - lam) * acc[m][n][r]
                                               + lam * vi[(size_t)grow * D_MODEL + hh * HD + d];
                                TB[d * 72 + trow] = f2bf(vv);
                            }
                        }
                }
                __syncthreads();
                // store head: 64 d-rows x BM(=64) t, swizzled 16B chunks
                const int hs = blockIdx.x * (BN / 64) + pass;
                const int drow = tid >> 2;        // 0..63
                const int q4 = tid & 3;
#pragma unroll
                for (int cc = 0; cc < 2; ++cc) {
                    const int cg = q4 * 2 + cc;   // chunk 0..7 (8 t each)
                    const int cw = cg ^ (drow & 7);
                    const ushort8 val = *(const ushort8*)&TB[drow * 72 + cg * 8];
                    *(ushort8*)&((ushort_t*)Cv)[(size_t)(hs * 64 + drow) * 2048
                                                + row0 + cw * 8] = val;
                }
            }
        } else {
#pragma unroll
            for (int m = 0; m < MF; ++m)
#pragma unroll
                for (int r = 0; r < 4; ++r) {
                    const int row = row0 + wr * WM + m * 16 + g4 * 4 + r;
                    float s = acc[m][0][r] * acc[m][0][r] + acc[m][1][r] * acc[m][1][r]
                            + acc[m][2][r] * acc[m][2][r] + acc[m][3][r] * acc[m][3][r];
                    s += __shfl_xor(s, 1, 64);
                    s += __shfl_xor(s, 2, 64);
                    s += __shfl_xor(s, 4, 64);
                    s += __shfl_xor(s, 8, 64);
                    const float rq = rsqrtf(s * (1.0f / 64.0f) + RMS_EPS);
                    float a[4];
#pragma unroll
                    for (int n = 0; n < 4; ++n) a[n] = acc[m][n][r] * rq;
                    // RoPE via precomputed table (pair d, d+32 = frag n, n+2)
                    const float2 cs0 = rtab[row * 32 + l16];
                    const float2 cs1 = rtab[row * 32 + 16 + l16];
#pragma unroll
                    for (int n = 0; n < 2; ++n) {
                        const float c  = n ? cs1.x : cs0.x;
                        const float sn = n ? cs1.y : cs0.y;
                        const float a0 = a[n], a2 = a[n + 2];
                        a[n]     = a0 * c + a2 * sn;
                        a[n + 2] = -a0 * sn + a2 * c;
                    }
#pragma unroll
                    for (int n = 0; n < 4; ++n) {
                        const int d = n * 16 + l16;
                        int col;
                        if (z == 1)
                            col = hh * HD + ((((d >> 3) ^ (row & 7)) << 3) | (d & 7));
                        else
                            col = hh * HD + d;
                        ((ushort_t*)Cv)[(size_t)row * D_MODEL + col] = f2bf(a[n]);
                    }
                }
        }
    }
}

// ---------------------------------------------------------------------------
// Flash attention v8 (r16 verbatim): K AND V via global_load_lds dbuf LDS
// (V source pre-transposed vT[h][d][t]); one barrier/iter; split-K; swapped
// QK^T; cvt_pk P-stores.
// ---------------------------------------------------------------------------
__global__ __launch_bounds__(256, 3) void attn_mfma(const ushort_t* __restrict__ qb,
                                                    const ushort_t* __restrict__ kb,
                                                    const ushort_t* __restrict__ vT,
                                                    const float* __restrict__ sink,
                                                    ushort_t* __restrict__ yb,
                                                    float* __restrict__ part_acc,
                                                    float* __restrict__ part_ml) {
    const int b = blockIdx.x;
    int h, qt, kt0, kt1, mode;   // mode 0 = full->y, 1/2 = partial half 0/1
    if (b < 512) {
        qt = 31 - (b >> 5);
        const int rem = b & 31;
        h = rem >> 1;
        const int half = rem & 1;
        const int mid = (qt + 1) >> 1;
        kt0 = half ? mid : 0;
        kt1 = half ? (qt + 1) : mid;
        mode = 1 + half;
    } else {
        const int rem = b - 512;
        qt = 15 - (rem >> 4);
        h = rem & 15;
        kt0 = 0; kt1 = qt + 1; mode = 0;
    }

    __shared__ ushort_t Kl[2][64 * 64];     // K tiles (swizzled rows), dbuf
    __shared__ ushort_t Vl[2][64 * 64];     // V^T tiles (swizzled rows), dbuf
    __shared__ ushort_t Pl[4][16][72];      // per-wave P

    const int tid  = threadIdx.x;
    const int w    = tid >> 6;
    const int lane = tid & 63;
    const int l16  = lane & 15;
    const int g4   = lane >> 4;

    const size_t qoff = (size_t)(qt * 64 + w * 16 + l16) * D_MODEL + h * HD;
    const short8 q0 = *(const short8*)&qb[qoff + 8 * g4];
    const short8 q1 = *(const short8*)&qb[qoff + 32 + 8 * g4];

    const int srow8  = w * 16 + (lane >> 3);   // staging row (+ i*8)
    const int scol_l = (lane & 7) * 8;

    // prologue: DMA K tile kt0 (rows=keys) and V^T tile kt0 (rows=d)
#pragma unroll
    for (int i = 0; i < 2; ++i) {
        gl_lds16(kb + ((size_t)(kt0 * 64 + srow8 + i * 8) << 10) + h * HD + scol_l,
                 &Kl[kt0 & 1][w * 1024 + i * 512]);
        gl_lds16(vT + ((size_t)(h * 64 + srow8 + i * 8) << 11) + kt0 * 64 + scol_l,
                 &Vl[kt0 & 1][w * 1024 + i * 512]);
    }

    float m = -INFINITY, lsum = 0.0f;
    f32x4 acc[4];
#pragma unroll
    for (int d = 0; d < 4; ++d) acc[d] = (f32x4){0.0f, 0.0f, 0.0f, 0.0f};

    for (int kt = kt0; kt < kt1; ++kt) {
        const int cur = kt & 1;

        __syncthreads();   // drains DMA[cur]; all prev reads of [cur^1] done

        // earliest legal DMA issue for next tile (into the just-freed buffer)
        if (kt + 1 < kt1) {
            const int nxt = cur ^ 1;
#pragma unroll
            for (int i = 0; i < 2; ++i) {
                gl_lds16(kb + ((size_t)((kt + 1) * 64 + srow8 + i * 8) << 10) + h * HD + scol_l,
                         &Kl[nxt][w * 1024 + i * 512]);
                gl_lds16(vT + ((size_t)(h * 64 + srow8 + i * 8) << 11) + (kt + 1) * 64 + scol_l,
                         &Vl[nxt][w * 1024 + i * 512]);
            }
        }

        // ---- K A-frags from LDS (swizzled), S^T = K Q^T ----
        f32x4 sf[4];
#pragma unroll
        for (int s = 0; s < 4; ++s) {
            const int row = s * 16 + l16;
            const int swz = l16 & 7;
            const short8 ka0 = *(const short8*)&Kl[cur][row * 64 + ((g4 ^ swz) << 3)];
            const short8 ka1 = *(const short8*)&Kl[cur][row * 64 + (((g4 + 4) ^ swz) << 3)];
            f32x4 t = (f32x4){0.0f, 0.0f, 0.0f, 0.0f};
            t = __builtin_amdgcn_mfma_f32_16x16x32_bf16(ka0, q0, t, 0, 0, 0);
            t = __builtin_amdgcn_mfma_f32_16x16x32_bf16(ka1, q1, t, 0, 0, 0);
            sf[s] = t;
        }

        float mt = -INFINITY;
        if (kt == qt) {
            const int ql = w * 16 + l16;
#pragma unroll
            for (int s = 0; s < 4; ++s)
#pragma unroll
                for (int r = 0; r < 4; ++r) {
                    const float sc = sf[s][r] * 0.125f;
                    sf[s][r] = (s * 16 + g4 * 4 + r > ql) ? -INFINITY : sc;
                    mt = fmaxf(mt, sf[s][r]);
                }
        } else {
#pragma unroll
            for (int s = 0; s < 4; ++s)
#pragma unroll
                for (int r = 0; r < 4; ++r) {
                    sf[s][r] *= 0.125f;
                    mt = fmaxf(mt, sf[s][r]);
                }
        }
        mt = fmaxf(mt, __shfl_xor(mt, 16, 64));
        mt = fmaxf(mt, __shfl_xor(mt, 32, 64));

        const float mnew = fmaxf(m, mt);
        const float corr = __expf(m - mnew);
        m = mnew;

        float ps = 0.0f;
#pragma unroll
        for (int s = 0; s < 4; ++s) {
            const float e0 = __expf(sf[s][0] - m);
            const float e1 = __expf(sf[s][1] - m);
            const float e2 = __expf(sf[s][2] - m);
            const float e3 = __expf(sf[s][3] - m);
            ps += (e0 + e1) + (e2 + e3);
            uint2 pk;
            pk.x = cvt_pk_bf16(e0, e1);
            pk.y = cvt_pk_bf16(e2, e3);
            *(uint2*)&Pl[w][l16][s * 16 + g4 * 4] = pk;
        }
        ps += __shfl_xor(ps, 16, 64);
        ps += __shfl_xor(ps, 32, 64);
        lsum = lsum * corr + ps;

        float corrq[4];
#pragma unroll
        for (int r = 0; r < 4; ++r) corrq[r] = __shfl(corr, g4 * 4 + r, 64);
#pragma unroll
        for (int d = 0; d < 4; ++d)
#pragma unroll
            for (int r = 0; r < 4; ++r) acc[d][r] *= corrq[r];

        // ---- PV: B-frags straight from Vl[cur] (V^T rows, swizzled) ----
        const short8 pa0 = *(const short8*)&Pl[w][l16][8 * g4];
        const short8 pa1 = *(const short8*)&Pl[w][l16][32 + 8 * g4];
#pragma unroll
        for (int d = 0; d < 4; ++d) {
            const int row = d * 16 + l16;
            const int swz = l16 & 7;
            const short8 v0 = *(const short8*)&Vl[cur][row * 64 + ((g4 ^ swz) << 3)];
            const short8 v1 = *(const short8*)&Vl[cur][row * 64 + (((g4 + 4) ^ swz) << 3)];
            acc[d] = __builtin_amdgcn_mfma_f32_16x16x32_bf16(pa0, v0, acc[d], 0, 0, 0);
            acc[d] = __builtin_amdgcn_mfma_f32_16x16x32_bf16(pa1, v1, acc[d], 0, 0, 0);
        }
    }

    if (mode == 0) {
        const float lse = m + __logf(lsum);
        const float scale = 1.0f / (1.0f + __expf(-(lse - sink[h])));
        const float fv = scale / lsum;
        float fq[4];
#pragma unroll
        for (int r = 0; r < 4; ++r) fq[r] = __shfl(fv, g4 * 4 + r, 64);
#pragma unroll
        for (int r = 0; r < 4; ++r) {
            const size_t yoff = (size_t)(qt * 64 + w * 16 + g4 * 4 + r) * D_MODEL + h * HD + l16;
#pragma unroll
            for (int d = 0; d < 4; ++d)
                yb[yoff + d * 16] = f2bf(acc[d][r] * fq[r]);
        }
    } else {
        const int pi = ((qt - 16) * 16 + h) * 2 + (mode - 1);
        if (g4 == 0) {
            float* ml = part_ml + (size_t)pi * 128;
            ml[w * 16 + l16]      = m;
            ml[64 + w * 16 + l16] = lsum;
        }
        float* pa = part_acc + (size_t)pi * 4096;
#pragma unroll
        for (int r = 0; r < 4; ++r) {
            const int row = w * 16 + g4 * 4 + r;
#pragma unroll
            for (int d = 0; d < 4; ++d)
                pa[row * 64 + d * 16 + l16] = acc[d][r];
        }
    }
}

// ---------------------------------------------------------------------------
// Merge the two key-half partials for qt>=16 and apply sink scaling.
// ---------------------------------------------------------------------------
__global__ __launch_bounds__(256) void attn_combine(const float* __restrict__ part_acc,
                                                    const float* __restrict__ part_ml,
                                                    const float* __restrict__ sink,
                                                    ushort_t* __restrict__ yb) {
    const int si = blockIdx.x;          // (qt-16)*16 + h
    const int h  = si & 15;
    const int qt = 16 + (si >> 4);
    const int t  = threadIdx.x;
    const int row = t >> 2;
    const int c0  = (t & 3) * 16;

    const float* a0 = part_acc + ((size_t)si * 2) * 4096 + row * 64 + c0;
    const float* a1 = a0 + 4096;
    const float* ml = part_ml + (size_t)si * 2 * 128;
    const float m0 = ml[row],       l0 = ml[64 + row];
    const float m1 = ml[128 + row], l1 = ml[192 + row];
    const float M  = fmaxf(m0, m1);
    const float e0 = __expf(m0 - M), e1 = __expf(m1 - M);
    const float l  = l0 * e0 + l1 * e1;
    const float lse = M + __logf(l);
    const float scale = 1.0f / (1.0f + __expf(-(lse - sink[h])));
    const float f = scale / l;

    ushort8 o[2];
#pragma unroll
    for (int j = 0; j < 16; ++j) {
        const float v = (a0[j] * e0 + a1[j] * e1) * f;
        o[j >> 3][j & 7] = f2bf(v);
    }
    ushort_t* yp = yb + (size_t)(qt * 64 + row) * D_MODEL + h * HD + c0;
    *(ushort8*)yp       = o[0];
    *(ushort8*)(yp + 8) = o[1];
}

// ---------------------------------------------------------------------------
extern "C" void kernel_launch(void* const* d_in, const int* in_sizes, int n_in,
                              void* d_out, int out_size, void* d_ws, size_t ws_size,
                              hipStream_t stream) {
    const float* x    = (const float*)d_in[0];
    const float* vi   = (const float*)d_in[1];
    const float* Wq   = (const float*)d_in[2];
    const float* Wk   = (const float*)d_in[3];
    const float* Wv   = (const float*)d_in[4];
    const float* Wo   = (const float*)d_in[5];
    const float* lamb = (const float*)d_in[6];
    const float* sink = (const float*)d_in[7];
    float* out = (float*)d_out;

    const size_t TD = (size_t)T_SEQ * D_MODEL;    // 2M elts
    const size_t WD = (size_t)D_MODEL * D_MODEL;  // 1M elts
    ushort_t* qbuf = (ushort_t*)d_ws;             // [ 0, 4)MB
    ushort_t* kbuf = qbuf + TD;                   // [ 4, 8)MB
    ushort_t* vbuf = kbuf + TD;                   // [ 8,12)MB  (= vT[h][d][t])
    ushort_t* yb   = vbuf + TD;                   // [12,16)MB
    ushort_t* wob  = yb + TD;                     // [16,18)MB
    ushort_t* xb   = wob + WD;                    // [18,22)MB
    ushort_t* wqb  = xb + TD;                     // [22,24)MB
    ushort_t* wkb  = wqb + WD;                    // [24,26)MB
    ushort_t* wvb  = wkb + WD;                    // [26,28)MB
    float2*   rtab = (float2*)(wvb + WD);         // [28,28.5)MB RoPE table
    // attn partials overlay the staging buffers (dead after the QKV GEMM):
    float* part_acc = (float*)xb;                 // 8 MB  [18,26)MB
    float* part_ml  = (float*)wvb;                // 256 KB in [26,28)MB

    cast_to_bf16<<<dim3(512, 7), 256, 0, stream>>>(x, Wq, Wk, Wv, Wo,
                                                   xb, wqb, wkb, wvb, wob, rtab);

    // fused QKV projection + v-blend + RMSNorm + RoPE + K-swizzle + V-transpose
    gemm_bf16_nt<64, 128, 2, 2, 1><<<dim3(D_MODEL / 128, T_SEQ / 64, 3), 256, 0, stream>>>(
        xb, wqb, wkb, wvb, qbuf, kbuf, vbuf, vi, lamb, rtab, T_SEQ, D_MODEL, D_MODEL);

    attn_mfma<<<dim3(768), 256, 0, stream>>>(qbuf, kbuf, vbuf, sink, yb,
                                             part_acc, part_ml);
    attn_combine<<<dim3(256), 256, 0, stream>>>(part_acc, part_ml, sink, yb);

    gemm_bf16_nt<64, 64, 2, 2, 0><<<dim3(D_MODEL / 64, T_SEQ / 64, 1), 256, 0, stream>>>(
        yb, wob, wob, wob, out, out, out, nullptr, nullptr, nullptr,
        T_SEQ, D_MODEL, D_MODEL);
}